// Round 5
// baseline (391.785 us; speedup 1.0000x reference)
//
#include <hip/hip_runtime.h>
#include <hip/hip_bf16.h>
#include <math.h>

#define DD 768
#define BB 32
#define PP 512
#define TT 512
#define CC 97
#define THRESH 0.8f
#define BK 32

typedef __attribute__((ext_vector_type(8))) short short8;
typedef __attribute__((ext_vector_type(4))) float f32x4;

__device__ __forceinline__ void gload16(const void* g, void* l) {
    __builtin_amdgcn_global_load_lds(
        (const __attribute__((address_space(1))) unsigned int*)g,
        (__attribute__((address_space(3))) unsigned int*)l, 16, 0, 0);
}

__device__ __forceinline__ ushort4 pack4(float4 v, float s) {
    __hip_bfloat16 a = __float2bfloat16(v.x * s), b = __float2bfloat16(v.y * s),
                   c = __float2bfloat16(v.z * s), d = __float2bfloat16(v.w * s);
    ushort4 o;
    o.x = *(unsigned short*)&a; o.y = *(unsigned short*)&b;
    o.z = *(unsigned short*)&c; o.w = *(unsigned short*)&d;
    return o;
}

// ---------------- stage 1a: normalize entity pairs (float4 vectorized) -------
// row = 1536 floats = 384 float4 (aligned: 6144B rows). Thread t owns f4 chunk
// t (all) and chunk 256+t (t<128). Chunks <192 = head, >=192 = tail.
__global__ void norm_pairs_kernel(const float* __restrict__ pairs,
                                  __hip_bfloat16* __restrict__ ph,
                                  __hip_bfloat16* __restrict__ pt) {
    int row = blockIdx.x;            // B*P rows
    int t = threadIdx.x;             // 256 threads
    const float4* s4 = (const float4*)(pairs + (size_t)row * (2 * DD));
    float4 v0 = s4[t];
    float4 v1 = make_float4(0.f, 0.f, 0.f, 0.f);
    if (t < 128) v1 = s4[256 + t];
    float d0 = v0.x * v0.x + v0.y * v0.y + v0.z * v0.z + v0.w * v0.w;
    float d1 = v1.x * v1.x + v1.y * v1.y + v1.z * v1.z + v1.w * v1.w;
    float sh = (t < 192) ? d0 : 0.f;
    float st = ((t >= 192) ? d0 : 0.f) + d1;

    for (int off = 32; off; off >>= 1) {
        sh += __shfl_down(sh, off);
        st += __shfl_down(st, off);
    }
    __shared__ float red[2][5];
    int wid = t >> 6, lane = t & 63;
    if (lane == 0) { red[0][wid] = sh; red[1][wid] = st; }
    __syncthreads();
    if (t == 0) {
        float a = red[0][0] + red[0][1] + red[0][2] + red[0][3];
        float b = red[1][0] + red[1][1] + red[1][2] + red[1][3];
        red[0][4] = 1.0f / fmaxf(sqrtf(a), 1e-8f);
        red[1][4] = 1.0f / fmaxf(sqrtf(b), 1e-8f);
    }
    __syncthreads();
    float ih = red[0][4], it = red[1][4];
    ushort4* dh = (ushort4*)(ph + (size_t)row * DD);
    ushort4* dt = (ushort4*)(pt + (size_t)row * DD);
    ushort4 o0 = pack4(v0, (t < 192) ? ih : it);
    if (t < 192) dh[t] = o0; else dt[t - 192] = o0;
    if (t < 128) dt[t + 64] = pack4(v1, it);
}

// ---------------- stage 1b: normalize triplets (rows misaligned, scalar) -----
__global__ void norm_trip_kernel(const float* __restrict__ trip,
                                 __hip_bfloat16* __restrict__ gh,
                                 __hip_bfloat16* __restrict__ gt,
                                 int* __restrict__ rel) {
    int row = blockIdx.x;            // B*T rows
    int tid = threadIdx.x;
    const float* src = trip + (size_t)row * (2 * DD + 1);

    float xh[3], xt[3];
    float sh = 0.f, st = 0.f;
#pragma unroll
    for (int j = 0; j < 3; ++j) {
        xh[j] = src[j * 256 + tid];
        xt[j] = src[DD + 1 + j * 256 + tid];
        sh += xh[j] * xh[j];
        st += xt[j] * xt[j];
    }
    for (int off = 32; off; off >>= 1) {
        sh += __shfl_down(sh, off);
        st += __shfl_down(st, off);
    }
    __shared__ float red[2][5];
    int wid = tid >> 6, lane = tid & 63;
    if (lane == 0) { red[0][wid] = sh; red[1][wid] = st; }
    __syncthreads();
    if (tid == 0) {
        float a = red[0][0] + red[0][1] + red[0][2] + red[0][3];
        float b = red[1][0] + red[1][1] + red[1][2] + red[1][3];
        red[0][4] = 1.0f / fmaxf(sqrtf(a), 1e-8f);
        red[1][4] = 1.0f / fmaxf(sqrtf(b), 1e-8f);
        rel[row] = (int)src[DD];
    }
    __syncthreads();
    float ih = red[0][4], it = red[1][4];
    __hip_bfloat16* dh = gh + (size_t)row * DD;
    __hip_bfloat16* dt = gt + (size_t)row * DD;
#pragma unroll
    for (int j = 0; j < 3; ++j) {
        dh[j * 256 + tid] = __float2bfloat16(xh[j] * ih);
        dt[j * 256 + tid] = __float2bfloat16(xt[j] * it);
    }
}

// ---------------- stage 2: gload_lds dual-GEMM, 64x64 wave tiles -------------
// Block: 512 thr = 8 waves. Tile: 128p x 128t of one batch. Waves 0-3 H-sims
// (2x2 grid of 64x64 quadrants), waves 4-7 T-sims (same quadrants). BK=32,
// double-buffered 2x32KB LDS staged via global_load_lds w16 (linear dest).
// One barrier per K-step; its vmcnt drain lands the prefetched next tile.
// Epilogue: lane-aligned H<->T exchange via LDS (R2 pattern), block argmax
// over 128 t -> cand arrays; merge kernel folds the 4 t-blocks.
__global__ __launch_bounds__(512, 4) void match_kernel(
        const __hip_bfloat16* __restrict__ ph, const __hip_bfloat16* __restrict__ pt,
        const __hip_bfloat16* __restrict__ gh, const __hip_bfloat16* __restrict__ gt,
        float* __restrict__ cand_v, int* __restrict__ cand_t) {
    __shared__ __align__(16) char smem[65536];   // 2 bufs x (Ah8K|At8K|Bh8K|Bt8K)

    // XCD swizzle (512 blocks, %8==0 -> bijective): XCD k gets batches 4k..4k+3
    int bid = blockIdx.x;
    int swz = (bid & 7) * 64 + (bid >> 3);
    int b = swz >> 4, sub = swz & 15;
    int pblk = sub >> 2, tblk = sub & 3;         // 4 p-blocks x 4 t-blocks

    int tid = threadIdx.x;
    int w = tid >> 6, l = tid & 63;
    int l15 = l & 15, lg = l >> 4;

    const __hip_bfloat16* Ah_g = ph + ((size_t)b * PP + pblk * 128) * DD;
    const __hip_bfloat16* At_g = pt + ((size_t)b * PP + pblk * 128) * DD;
    const __hip_bfloat16* Bh_g = gh + ((size_t)b * TT + tblk * 128) * DD;
    const __hip_bfloat16* Bt_g = gt + ((size_t)b * TT + tblk * 128) * DD;

    // staging map: tile = 128 rows x 64B; thread -> (row = tid>>2, 16B lane ln)
    int rowq = tid >> 2;
    int ln8 = (tid & 3) * 8;
    size_t srow = (size_t)rowq * DD + ln8;

#define STAGE(c, step)                                                        \
    do {                                                                      \
        size_t ko = srow + (size_t)(step) * BK;                               \
        char* lb = smem + (c) * 32768 + (size_t)tid * 16;                     \
        gload16(Ah_g + ko, lb);                                               \
        gload16(At_g + ko, lb + 8192);                                        \
        gload16(Bh_g + ko, lb + 16384);                                       \
        gload16(Bt_g + ko, lb + 24576);                                       \
    } while (0)

    // per-wave fragment addressing (row pitch 64B, lane k-slot = lg*16)
    int qi = w & 3, qr = qi >> 1, qc = qi & 1;
    int Aoff = (w < 4) ? 0 : 8192;
    int Boff = (w < 4) ? 16384 : 24576;
    int oA[4], oB[4];
#pragma unroll
    for (int i = 0; i < 4; ++i) oA[i] = Aoff + (qr * 64 + i * 16 + l15) * 64 + lg * 16;
#pragma unroll
    for (int j = 0; j < 4; ++j) oB[j] = Boff + (qc * 64 + j * 16 + l15) * 64 + lg * 16;

    f32x4 acc[4][4];
#pragma unroll
    for (int i = 0; i < 4; ++i)
#pragma unroll
        for (int j = 0; j < 4; ++j) acc[i][j] = (f32x4){0.f, 0.f, 0.f, 0.f};

    int cur = 0;
    STAGE(0, 0);
    __syncthreads();

    for (int t = 0; t < DD / BK; ++t) {
        if (t < DD / BK - 1) STAGE(cur ^ 1, t + 1);
        const char* bp = smem + cur * 32768;
        short8 af[4], bf[4];
#pragma unroll
        for (int i = 0; i < 4; ++i) af[i] = *(const short8*)(bp + oA[i]);
#pragma unroll
        for (int j = 0; j < 4; ++j) bf[j] = *(const short8*)(bp + oB[j]);
#pragma unroll
        for (int i = 0; i < 4; ++i)
#pragma unroll
            for (int j = 0; j < 4; ++j)
                acc[i][j] = __builtin_amdgcn_mfma_f32_16x16x32_bf16(af[i], bf[j], acc[i][j], 0, 0, 0);
        __syncthreads();          // drains vmcnt (next tile landed) + lgkm
        cur ^= 1;
    }
#undef STAGE

    // epilogue: H (waves 0-3) x T (waves 4-7) combine, lane-aligned via LDS
    float (*xch)[64][16] = (float (*)[64][16])(void*)smem;        // 16KB
    float (*bwv)[2] = (float (*)[2])(void*)(smem + 16384);
    int   (*bwt)[2] = (int   (*)[2])(void*)(smem + 17408);
    int wp = w & 3;
    for (int i = 0; i < 4; ++i) {
        if (w >= 4) {
#pragma unroll
            for (int j = 0; j < 4; ++j)
#pragma unroll
                for (int r = 0; r < 4; ++r)
                    xch[wp][l][j * 4 + r] = acc[i][j][r];
        }
        __syncthreads();
        if (w < 4) {
#pragma unroll
            for (int r = 0; r < 4; ++r) {
                float bv = -INFINITY; int bt = 0x7fffffff;
#pragma unroll
                for (int j = 0; j < 4; ++j) {
                    float h = acc[i][j][r];
                    float tv = xch[wp][l][j * 4 + r];
                    bool ok = (h > THRESH) && (tv > THRESH);
                    float sc = ok ? 0.5f * (h + tv) : -INFINITY;
                    int tg = qc * 64 + j * 16 + l15;
                    if (sc > bv || (sc == bv && tg < bt)) { bv = sc; bt = tg; }
                }
#pragma unroll
                for (int m = 1; m < 16; m <<= 1) {
                    float v2 = __shfl_xor(bv, m);
                    int t2 = __shfl_xor(bt, m);
                    if (v2 > bv || (v2 == bv && t2 < bt)) { bv = v2; bt = t2; }
                }
                if (l15 == 0) {
                    int p = qr * 64 + i * 16 + lg * 4 + r;
                    bwv[p][qc] = bv;
                    bwt[p][qc] = bt;
                }
            }
        }
        __syncthreads();
    }

    if (tid < 128) {
        float v = bwv[tid][0]; int t1 = bwt[tid][0];
        float v2 = bwv[tid][1]; int t2 = bwt[tid][1];
        if (v2 > v || (v2 == v && t2 < t1)) { v = v2; t1 = t2; }
        int grow = b * PP + pblk * 128 + tid;
        cand_v[(size_t)grow * 4 + tblk] = v;
        cand_t[(size_t)grow * 4 + tblk] = (v > -INFINITY) ? (tblk * 128 + t1) : 0x7fffffff;
    }
}

// ---------------- stage 2b: merge 4 t-blocks -> target class -----------------
__global__ void merge_kernel(const float* __restrict__ cand_v,
                             const int* __restrict__ cand_t,
                             const int* __restrict__ rel,
                             int* __restrict__ tgt) {
    int row = blockIdx.x * 256 + threadIdx.x;    // B*P rows
    float v = -INFINITY; int t = 0x7fffffff;
#pragma unroll
    for (int k = 0; k < 4; ++k) {
        float v2 = cand_v[(size_t)row * 4 + k];
        int t2 = cand_t[(size_t)row * 4 + k];
        if (v2 > v || (v2 == v && t2 < t)) { v = v2; t = t2; }
    }
    int b = row >> 9;
    tgt[row] = (v > -INFINITY) ? rel[b * TT + t] : 0;
}

// ---------------- stage 3: per-row NLL from log-softmax ----------------------
__global__ void nll_kernel(const float* __restrict__ preds,
                           const int* __restrict__ tgt,
                           float* __restrict__ partials) {
    int w = threadIdx.x >> 6, l = threadIdx.x & 63;
    int row = blockIdx.x * 4 + w;
    const float* x = preds + (size_t)row * CC;

    float a = x[l];
    float b2 = (l + 64 < CC) ? x[l + 64] : -INFINITY;
    float mx = fmaxf(a, b2);
    for (int m = 32; m; m >>= 1) mx = fmaxf(mx, __shfl_xor(mx, m));
    float e = __expf(a - mx) + ((l + 64 < CC) ? __expf(b2 - mx) : 0.0f);
    for (int m = 32; m; m >>= 1) e += __shfl_xor(e, m);

    __shared__ float part[4];
    if (l == 0) {
        int tg = tgt[row];
        part[w] = mx + logf(e) - x[tg];
    }
    __syncthreads();
    if (threadIdx.x == 0)
        partials[blockIdx.x] = part[0] + part[1] + part[2] + part[3];
}

// ---------------- stage 4: final mean ----------------------------------------
__global__ void final_reduce_kernel(const float* __restrict__ partials, int n,
                                    float* __restrict__ out) {
    float s = 0.f;
    for (int i = threadIdx.x; i < n; i += 256) s += partials[i];
    for (int m = 32; m; m >>= 1) s += __shfl_xor(s, m);
    __shared__ float ps[4];
    if ((threadIdx.x & 63) == 0) ps[threadIdx.x >> 6] = s;
    __syncthreads();
    if (threadIdx.x == 0)
        out[0] = (ps[0] + ps[1] + ps[2] + ps[3]) / (float)(BB * PP);
}

extern "C" void kernel_launch(void* const* d_in, const int* in_sizes, int n_in,
                              void* d_out, int out_size, void* d_ws, size_t ws_size,
                              hipStream_t stream) {
    const float* pairs = (const float*)d_in[0];  // [B,P,1536]
    const float* preds = (const float*)d_in[1];  // [B,P,97]
    const float* trip  = (const float*)d_in[2];  // [B,T,1537]
    float* out = (float*)d_out;

    char* ws = (char*)d_ws;
    size_t vec_bytes = (size_t)BB * PP * DD * sizeof(__hip_bfloat16);  // 25,165,824
    __hip_bfloat16* ph = (__hip_bfloat16*)(ws);
    __hip_bfloat16* pt = (__hip_bfloat16*)(ws + vec_bytes);
    __hip_bfloat16* gh = (__hip_bfloat16*)(ws + 2 * vec_bytes);
    __hip_bfloat16* gt = (__hip_bfloat16*)(ws + 3 * vec_bytes);
    char* p = ws + 4 * vec_bytes;
    int* rel = (int*)p;              p += (size_t)BB * TT * sizeof(int);        // 64KB
    int* tgt = (int*)p;              p += (size_t)BB * PP * sizeof(int);        // 64KB
    float* cand_v = (float*)p;       p += (size_t)BB * PP * 4 * sizeof(float);  // 256KB
    int* cand_t = (int*)p;           p += (size_t)BB * PP * 4 * sizeof(int);    // 256KB
    float* partials = (float*)p;                                                // 16KB

    norm_pairs_kernel<<<BB * PP, 256, 0, stream>>>(pairs, ph, pt);
    norm_trip_kernel<<<BB * TT, 256, 0, stream>>>(trip, gh, gt, rel);
    match_kernel<<<BB * 16, 512, 0, stream>>>(ph, pt, gh, gt, cand_v, cand_t);
    merge_kernel<<<BB * PP / 256, 256, 0, stream>>>(cand_v, cand_t, rel, tgt);
    nll_kernel<<<BB * PP / 4, 256, 0, stream>>>(preds, tgt, partials);
    final_reduce_kernel<<<1, 256, 0, stream>>>(partials, BB * PP / 4, out);
}

// Round 6
// 382.362 us; speedup vs baseline: 1.0246x; 1.0246x over previous
//
#include <hip/hip_runtime.h>
#include <hip/hip_bf16.h>
#include <math.h>

#define DD 768
#define BB 32
#define PP 512
#define TT 512
#define CC 97
#define THRESH 0.8f
#define BK 32

typedef __attribute__((ext_vector_type(8))) short short8;
typedef __attribute__((ext_vector_type(4))) float f32x4;

__device__ __forceinline__ void gload16(const void* g, void* l) {
    __builtin_amdgcn_global_load_lds(
        (const __attribute__((address_space(1))) unsigned int*)g,
        (__attribute__((address_space(3))) unsigned int*)l, 16, 0, 0);
}

__device__ __forceinline__ ushort4 pack4(float4 v, float s) {
    __hip_bfloat16 a = __float2bfloat16(v.x * s), b = __float2bfloat16(v.y * s),
                   c = __float2bfloat16(v.z * s), d = __float2bfloat16(v.w * s);
    ushort4 o;
    o.x = *(unsigned short*)&a; o.y = *(unsigned short*)&b;
    o.z = *(unsigned short*)&c; o.w = *(unsigned short*)&d;
    return o;
}

// ---------------- stage 1a: normalize entity pairs (float4 vectorized) -------
__global__ void norm_pairs_kernel(const float* __restrict__ pairs,
                                  __hip_bfloat16* __restrict__ ph,
                                  __hip_bfloat16* __restrict__ pt) {
    int row = blockIdx.x;            // B*P rows
    int t = threadIdx.x;             // 256 threads
    const float4* s4 = (const float4*)(pairs + (size_t)row * (2 * DD));
    float4 v0 = s4[t];
    float4 v1 = make_float4(0.f, 0.f, 0.f, 0.f);
    if (t < 128) v1 = s4[256 + t];
    float d0 = v0.x * v0.x + v0.y * v0.y + v0.z * v0.z + v0.w * v0.w;
    float d1 = v1.x * v1.x + v1.y * v1.y + v1.z * v1.z + v1.w * v1.w;
    float sh = (t < 192) ? d0 : 0.f;
    float st = ((t >= 192) ? d0 : 0.f) + d1;

    for (int off = 32; off; off >>= 1) {
        sh += __shfl_down(sh, off);
        st += __shfl_down(st, off);
    }
    __shared__ float red[2][5];
    int wid = t >> 6, lane = t & 63;
    if (lane == 0) { red[0][wid] = sh; red[1][wid] = st; }
    __syncthreads();
    if (t == 0) {
        float a = red[0][0] + red[0][1] + red[0][2] + red[0][3];
        float b = red[1][0] + red[1][1] + red[1][2] + red[1][3];
        red[0][4] = 1.0f / fmaxf(sqrtf(a), 1e-8f);
        red[1][4] = 1.0f / fmaxf(sqrtf(b), 1e-8f);
    }
    __syncthreads();
    float ih = red[0][4], it = red[1][4];
    ushort4* dh = (ushort4*)(ph + (size_t)row * DD);
    ushort4* dt = (ushort4*)(pt + (size_t)row * DD);
    ushort4 o0 = pack4(v0, (t < 192) ? ih : it);
    if (t < 192) dh[t] = o0; else dt[t - 192] = o0;
    if (t < 128) dt[t + 64] = pack4(v1, it);
}

// ---------------- stage 1b: normalize triplets (rows misaligned, scalar) -----
__global__ void norm_trip_kernel(const float* __restrict__ trip,
                                 __hip_bfloat16* __restrict__ gh,
                                 __hip_bfloat16* __restrict__ gt,
                                 int* __restrict__ rel) {
    int row = blockIdx.x;            // B*T rows
    int tid = threadIdx.x;
    const float* src = trip + (size_t)row * (2 * DD + 1);

    float xh[3], xt[3];
    float sh = 0.f, st = 0.f;
#pragma unroll
    for (int j = 0; j < 3; ++j) {
        xh[j] = src[j * 256 + tid];
        xt[j] = src[DD + 1 + j * 256 + tid];
        sh += xh[j] * xh[j];
        st += xt[j] * xt[j];
    }
    for (int off = 32; off; off >>= 1) {
        sh += __shfl_down(sh, off);
        st += __shfl_down(st, off);
    }
    __shared__ float red[2][5];
    int wid = tid >> 6, lane = tid & 63;
    if (lane == 0) { red[0][wid] = sh; red[1][wid] = st; }
    __syncthreads();
    if (tid == 0) {
        float a = red[0][0] + red[0][1] + red[0][2] + red[0][3];
        float b = red[1][0] + red[1][1] + red[1][2] + red[1][3];
        red[0][4] = 1.0f / fmaxf(sqrtf(a), 1e-8f);
        red[1][4] = 1.0f / fmaxf(sqrtf(b), 1e-8f);
        rel[row] = (int)src[DD];
    }
    __syncthreads();
    float ih = red[0][4], it = red[1][4];
    __hip_bfloat16* dh = gh + (size_t)row * DD;
    __hip_bfloat16* dt = gt + (size_t)row * DD;
#pragma unroll
    for (int j = 0; j < 3; ++j) {
        dh[j * 256 + tid] = __float2bfloat16(xh[j] * ih);
        dt[j * 256 + tid] = __float2bfloat16(xt[j] * it);
    }
}

// ---------------- stage 2: gload_lds dual-GEMM, 64x64 wave tiles -------------
// Block: 512 thr = 8 waves. Tile: 128p x 128t of one batch. Waves 0-3 H-sims
// (2x2 grid of 64x64 quadrants), waves 4-7 T-sims. BK=32, double-buffered
// 2x32KB LDS via global_load_lds w16 (LINEAR dest).
// Bank-conflict fix (rule 21, both sides): LDS slot s of row r holds source
// k-chunk s ^ ((r>>1)&3) (source pre-permuted within each 64B row-span, an
// involution, coalescing preserved); ds_read applies the same XOR. Group =
// (4*l15 + lg^((l15>>1)&3))%8 covers all 8 bank groups -> conflict-free.
// launch_bounds(512,2): reg cap 256, NO accumulator spill (R5's 1.6GB bug).
__global__ __launch_bounds__(512, 2) void match_kernel(
        const __hip_bfloat16* __restrict__ ph, const __hip_bfloat16* __restrict__ pt,
        const __hip_bfloat16* __restrict__ gh, const __hip_bfloat16* __restrict__ gt,
        float* __restrict__ cand_v, int* __restrict__ cand_t) {
    __shared__ __align__(16) char smem[65536];   // 2 bufs x (Ah8K|At8K|Bh8K|Bt8K)

    // XCD swizzle (512 blocks, %8==0 -> bijective)
    int bid = blockIdx.x;
    int swz = (bid & 7) * 64 + (bid >> 3);
    int b = swz >> 4, sub = swz & 15;
    int pblk = sub >> 2, tblk = sub & 3;         // 4 p-blocks x 4 t-blocks

    int tid = threadIdx.x;
    int w = tid >> 6, l = tid & 63;
    int l15 = l & 15, lg = l >> 4;

    const __hip_bfloat16* Ah_g = ph + ((size_t)b * PP + pblk * 128) * DD;
    const __hip_bfloat16* At_g = pt + ((size_t)b * PP + pblk * 128) * DD;
    const __hip_bfloat16* Bh_g = gh + ((size_t)b * TT + tblk * 128) * DD;
    const __hip_bfloat16* Bt_g = gt + ((size_t)b * TT + tblk * 128) * DD;

    // staging: thread -> LDS linear tid*16 = row (tid>>2), slot (tid&3).
    // source k-chunk = slot ^ ((row>>1)&3)  [row>>1 = tid>>3]
    int schunk = (tid & 3) ^ ((tid >> 3) & 3);
    size_t srow = (size_t)(tid >> 2) * DD + schunk * 8;

#define STAGE(c, step)                                                        \
    do {                                                                      \
        size_t ko = srow + (size_t)(step) * BK;                               \
        char* lb = smem + (c) * 32768 + (size_t)tid * 16;                     \
        gload16(Ah_g + ko, lb);                                               \
        gload16(At_g + ko, lb + 8192);                                        \
        gload16(Bh_g + ko, lb + 16384);                                       \
        gload16(Bt_g + ko, lb + 24576);                                       \
    } while (0)

    // per-wave fragment addressing (row pitch 64B, swizzled 16B slot)
    int qi = w & 3, qr = qi >> 1, qc = qi & 1;
    int Aoff = (w < 4) ? 0 : 8192;
    int Boff = (w < 4) ? 16384 : 24576;
    int slot = (lg ^ ((l15 >> 1) & 3));          // row bits beyond l15 are %4==0
    int oA[4], oB[4];
#pragma unroll
    for (int i = 0; i < 4; ++i) oA[i] = Aoff + (qr * 64 + i * 16 + l15) * 64 + slot * 16;
#pragma unroll
    for (int j = 0; j < 4; ++j) oB[j] = Boff + (qc * 64 + j * 16 + l15) * 64 + slot * 16;

    f32x4 acc[4][4];
#pragma unroll
    for (int i = 0; i < 4; ++i)
#pragma unroll
        for (int j = 0; j < 4; ++j) acc[i][j] = (f32x4){0.f, 0.f, 0.f, 0.f};

    int cur = 0;
    STAGE(0, 0);
    __syncthreads();

    for (int t = 0; t < DD / BK; ++t) {
        if (t < DD / BK - 1) STAGE(cur ^ 1, t + 1);
        const char* bp = smem + cur * 32768;
        short8 af[4], bf[4];
#pragma unroll
        for (int i = 0; i < 4; ++i) af[i] = *(const short8*)(bp + oA[i]);
#pragma unroll
        for (int j = 0; j < 4; ++j) bf[j] = *(const short8*)(bp + oB[j]);
#pragma unroll
        for (int i = 0; i < 4; ++i)
#pragma unroll
            for (int j = 0; j < 4; ++j)
                acc[i][j] = __builtin_amdgcn_mfma_f32_16x16x32_bf16(af[i], bf[j], acc[i][j], 0, 0, 0);
        __syncthreads();          // drains vmcnt (next tile landed) + lgkm
        cur ^= 1;
    }
#undef STAGE

    // epilogue: H (waves 0-3) x T (waves 4-7) combine, lane-aligned via LDS
    float (*xch)[64][16] = (float (*)[64][16])(void*)smem;        // 16KB
    float (*bwv)[2] = (float (*)[2])(void*)(smem + 16384);
    int   (*bwt)[2] = (int   (*)[2])(void*)(smem + 17408);
    int wp = w & 3;
    for (int i = 0; i < 4; ++i) {
        if (w >= 4) {
#pragma unroll
            for (int j = 0; j < 4; ++j)
#pragma unroll
                for (int r = 0; r < 4; ++r)
                    xch[wp][l][j * 4 + r] = acc[i][j][r];
        }
        __syncthreads();
        if (w < 4) {
#pragma unroll
            for (int r = 0; r < 4; ++r) {
                float bv = -INFINITY; int bt = 0x7fffffff;
#pragma unroll
                for (int j = 0; j < 4; ++j) {
                    float h = acc[i][j][r];
                    float tv = xch[wp][l][j * 4 + r];
                    bool ok = (h > THRESH) && (tv > THRESH);
                    float sc = ok ? 0.5f * (h + tv) : -INFINITY;
                    int tg = qc * 64 + j * 16 + l15;
                    if (sc > bv || (sc == bv && tg < bt)) { bv = sc; bt = tg; }
                }
#pragma unroll
                for (int m = 1; m < 16; m <<= 1) {
                    float v2 = __shfl_xor(bv, m);
                    int t2 = __shfl_xor(bt, m);
                    if (v2 > bv || (v2 == bv && t2 < bt)) { bv = v2; bt = t2; }
                }
                if (l15 == 0) {
                    int p = qr * 64 + i * 16 + lg * 4 + r;
                    bwv[p][qc] = bv;
                    bwt[p][qc] = bt;
                }
            }
        }
        __syncthreads();
    }

    if (tid < 128) {
        float v = bwv[tid][0]; int t1 = bwt[tid][0];
        float v2 = bwv[tid][1]; int t2 = bwt[tid][1];
        if (v2 > v || (v2 == v && t2 < t1)) { v = v2; t1 = t2; }
        int grow = b * PP + pblk * 128 + tid;
        cand_v[(size_t)grow * 4 + tblk] = v;
        cand_t[(size_t)grow * 4 + tblk] = (v > -INFINITY) ? (tblk * 128 + t1) : 0x7fffffff;
    }
}

// ---------------- stage 2b: merge 4 t-blocks -> target class -----------------
__global__ void merge_kernel(const float* __restrict__ cand_v,
                             const int* __restrict__ cand_t,
                             const int* __restrict__ rel,
                             int* __restrict__ tgt) {
    int row = blockIdx.x * 256 + threadIdx.x;    // B*P rows
    float v = -INFINITY; int t = 0x7fffffff;
#pragma unroll
    for (int k = 0; k < 4; ++k) {
        float v2 = cand_v[(size_t)row * 4 + k];
        int t2 = cand_t[(size_t)row * 4 + k];
        if (v2 > v || (v2 == v && t2 < t)) { v = v2; t = t2; }
    }
    int b = row >> 9;
    tgt[row] = (v > -INFINITY) ? rel[b * TT + t] : 0;
}

// ---------------- stage 3: per-row NLL from log-softmax ----------------------
__global__ void nll_kernel(const float* __restrict__ preds,
                           const int* __restrict__ tgt,
                           float* __restrict__ partials) {
    int w = threadIdx.x >> 6, l = threadIdx.x & 63;
    int row = blockIdx.x * 4 + w;
    const float* x = preds + (size_t)row * CC;

    float a = x[l];
    float b2 = (l + 64 < CC) ? x[l + 64] : -INFINITY;
    float mx = fmaxf(a, b2);
    for (int m = 32; m; m >>= 1) mx = fmaxf(mx, __shfl_xor(mx, m));
    float e = __expf(a - mx) + ((l + 64 < CC) ? __expf(b2 - mx) : 0.0f);
    for (int m = 32; m; m >>= 1) e += __shfl_xor(e, m);

    __shared__ float part[4];
    if (l == 0) {
        int tg = tgt[row];
        part[w] = mx + logf(e) - x[tg];
    }
    __syncthreads();
    if (threadIdx.x == 0)
        partials[blockIdx.x] = part[0] + part[1] + part[2] + part[3];
}

// ---------------- stage 4: final mean ----------------------------------------
__global__ void final_reduce_kernel(const float* __restrict__ partials, int n,
                                    float* __restrict__ out) {
    float s = 0.f;
    for (int i = threadIdx.x; i < n; i += 256) s += partials[i];
    for (int m = 32; m; m >>= 1) s += __shfl_xor(s, m);
    __shared__ float ps[4];
    if ((threadIdx.x & 63) == 0) ps[threadIdx.x >> 6] = s;
    __syncthreads();
    if (threadIdx.x == 0)
        out[0] = (ps[0] + ps[1] + ps[2] + ps[3]) / (float)(BB * PP);
}

extern "C" void kernel_launch(void* const* d_in, const int* in_sizes, int n_in,
                              void* d_out, int out_size, void* d_ws, size_t ws_size,
                              hipStream_t stream) {
    const float* pairs = (const float*)d_in[0];  // [B,P,1536]
    const float* preds = (const float*)d_in[1];  // [B,P,97]
    const float* trip  = (const float*)d_in[2];  // [B,T,1537]
    float* out = (float*)d_out;

    char* ws = (char*)d_ws;
    size_t vec_bytes = (size_t)BB * PP * DD * sizeof(__hip_bfloat16);  // 25,165,824
    __hip_bfloat16* ph = (__hip_bfloat16*)(ws);
    __hip_bfloat16* pt = (__hip_bfloat16*)(ws + vec_bytes);
    __hip_bfloat16* gh = (__hip_bfloat16*)(ws + 2 * vec_bytes);
    __hip_bfloat16* gt = (__hip_bfloat16*)(ws + 3 * vec_bytes);
    char* p = ws + 4 * vec_bytes;
    int* rel = (int*)p;              p += (size_t)BB * TT * sizeof(int);        // 64KB
    int* tgt = (int*)p;              p += (size_t)BB * PP * sizeof(int);        // 64KB
    float* cand_v = (float*)p;       p += (size_t)BB * PP * 4 * sizeof(float);  // 256KB
    int* cand_t = (int*)p;           p += (size_t)BB * PP * 4 * sizeof(int);    // 256KB
    float* partials = (float*)p;                                                // 16KB

    norm_pairs_kernel<<<BB * PP, 256, 0, stream>>>(pairs, ph, pt);
    norm_trip_kernel<<<BB * TT, 256, 0, stream>>>(trip, gh, gt, rel);
    match_kernel<<<BB * 16, 512, 0, stream>>>(ph, pt, gh, gt, cand_v, cand_t);
    merge_kernel<<<BB * PP / 256, 256, 0, stream>>>(cand_v, cand_t, rel, tgt);
    nll_kernel<<<BB * PP / 4, 256, 0, stream>>>(preds, tgt, partials);
    final_reduce_kernel<<<1, 256, 0, stream>>>(partials, BB * PP / 4, out);
}

// Round 7
// 125.650 us; speedup vs baseline: 3.1181x; 3.0431x over previous
//
#include <hip/hip_runtime.h>
#include <hip/hip_bf16.h>
#include <math.h>

#define DD 768
#define BB 32
#define PP 512
#define TT 512
#define CC 97
#define THRESH 0.8f
#define BK 32

typedef __attribute__((ext_vector_type(8))) short short8;
typedef __attribute__((ext_vector_type(4))) float f32x4;

__device__ __forceinline__ void gload16(const void* g, void* l) {
    __builtin_amdgcn_global_load_lds(
        (const __attribute__((address_space(1))) unsigned int*)g,
        (__attribute__((address_space(3))) unsigned int*)l, 16, 0, 0);
}

__device__ __forceinline__ ushort4 pack4(float4 v, float s) {
    __hip_bfloat16 a = __float2bfloat16(v.x * s), b = __float2bfloat16(v.y * s),
                   c = __float2bfloat16(v.z * s), d = __float2bfloat16(v.w * s);
    ushort4 o;
    o.x = *(unsigned short*)&a; o.y = *(unsigned short*)&b;
    o.z = *(unsigned short*)&c; o.w = *(unsigned short*)&d;
    return o;
}

// ---------------- stage 1a: normalize entity pairs (float4 vectorized) -------
__global__ void norm_pairs_kernel(const float* __restrict__ pairs,
                                  __hip_bfloat16* __restrict__ ph,
                                  __hip_bfloat16* __restrict__ pt) {
    int row = blockIdx.x;            // B*P rows
    int t = threadIdx.x;             // 256 threads
    const float4* s4 = (const float4*)(pairs + (size_t)row * (2 * DD));
    float4 v0 = s4[t];
    float4 v1 = make_float4(0.f, 0.f, 0.f, 0.f);
    if (t < 128) v1 = s4[256 + t];
    float d0 = v0.x * v0.x + v0.y * v0.y + v0.z * v0.z + v0.w * v0.w;
    float d1 = v1.x * v1.x + v1.y * v1.y + v1.z * v1.z + v1.w * v1.w;
    float sh = (t < 192) ? d0 : 0.f;
    float st = ((t >= 192) ? d0 : 0.f) + d1;

    for (int off = 32; off; off >>= 1) {
        sh += __shfl_down(sh, off);
        st += __shfl_down(st, off);
    }
    __shared__ float red[2][5];
    int wid = t >> 6, lane = t & 63;
    if (lane == 0) { red[0][wid] = sh; red[1][wid] = st; }
    __syncthreads();
    if (t == 0) {
        float a = red[0][0] + red[0][1] + red[0][2] + red[0][3];
        float b = red[1][0] + red[1][1] + red[1][2] + red[1][3];
        red[0][4] = 1.0f / fmaxf(sqrtf(a), 1e-8f);
        red[1][4] = 1.0f / fmaxf(sqrtf(b), 1e-8f);
    }
    __syncthreads();
    float ih = red[0][4], it = red[1][4];
    ushort4* dh = (ushort4*)(ph + (size_t)row * DD);
    ushort4* dt = (ushort4*)(pt + (size_t)row * DD);
    ushort4 o0 = pack4(v0, (t < 192) ? ih : it);
    if (t < 192) dh[t] = o0; else dt[t - 192] = o0;
    if (t < 128) dt[t + 64] = pack4(v1, it);
}

// ---------------- stage 1b: normalize triplets (rows misaligned, scalar) -----
__global__ void norm_trip_kernel(const float* __restrict__ trip,
                                 __hip_bfloat16* __restrict__ gh,
                                 __hip_bfloat16* __restrict__ gt,
                                 int* __restrict__ rel) {
    int row = blockIdx.x;            // B*T rows
    int tid = threadIdx.x;
    const float* src = trip + (size_t)row * (2 * DD + 1);

    float xh[3], xt[3];
    float sh = 0.f, st = 0.f;
#pragma unroll
    for (int j = 0; j < 3; ++j) {
        xh[j] = src[j * 256 + tid];
        xt[j] = src[DD + 1 + j * 256 + tid];
        sh += xh[j] * xh[j];
        st += xt[j] * xt[j];
    }
    for (int off = 32; off; off >>= 1) {
        sh += __shfl_down(sh, off);
        st += __shfl_down(st, off);
    }
    __shared__ float red[2][5];
    int wid = tid >> 6, lane = tid & 63;
    if (lane == 0) { red[0][wid] = sh; red[1][wid] = st; }
    __syncthreads();
    if (tid == 0) {
        float a = red[0][0] + red[0][1] + red[0][2] + red[0][3];
        float b = red[1][0] + red[1][1] + red[1][2] + red[1][3];
        red[0][4] = 1.0f / fmaxf(sqrtf(a), 1e-8f);
        red[1][4] = 1.0f / fmaxf(sqrtf(b), 1e-8f);
        rel[row] = (int)src[DD];
    }
    __syncthreads();
    float ih = red[0][4], it = red[1][4];
    __hip_bfloat16* dh = gh + (size_t)row * DD;
    __hip_bfloat16* dt = gt + (size_t)row * DD;
#pragma unroll
    for (int j = 0; j < 3; ++j) {
        dh[j * 256 + tid] = __float2bfloat16(xh[j] * ih);
        dt[j * 256 + tid] = __float2bfloat16(xt[j] * it);
    }
}

// ---------------- stage 2: gload_lds dual-GEMM, 64x64 wave tiles -------------
// Block: 512 thr = 8 waves. Tile: 128p x 128t of one batch. Waves 0-3 H-sims
// (2x2 grid of 64x64 quadrants), waves 4-7 T-sims. BK=32, double-buffered
// 2x32KB LDS via global_load_lds w16 (LINEAR dest, source k-chunk pre-XOR'd).
// R7 fixes: (1) accumulators are 16 NAMED f32x4 (no array -> no runtime
// indexing -> no scratch; R5/R6's 1.6GB WRITE_SIZE was the acc array demoted
// to scratch by the un-unrolled epilogue loop, rule #20). (2) epilogue H<->T
// exchange uses the same XOR quad-slot swizzle as the main loop (conflict-free).
__global__ __launch_bounds__(512, 2) void match_kernel(
        const __hip_bfloat16* __restrict__ ph, const __hip_bfloat16* __restrict__ pt,
        const __hip_bfloat16* __restrict__ gh, const __hip_bfloat16* __restrict__ gt,
        float* __restrict__ cand_v, int* __restrict__ cand_t) {
    __shared__ __align__(16) char smem[65536];   // 2 bufs x (Ah8K|At8K|Bh8K|Bt8K)

    // XCD swizzle (512 blocks, %8==0 -> bijective)
    int bid = blockIdx.x;
    int swz = (bid & 7) * 64 + (bid >> 3);
    int b = swz >> 4, sub = swz & 15;
    int pblk = sub >> 2, tblk = sub & 3;         // 4 p-blocks x 4 t-blocks

    int tid = threadIdx.x;
    int w = tid >> 6, l = tid & 63;
    int l15 = l & 15, lg = l >> 4;

    const __hip_bfloat16* Ah_g = ph + ((size_t)b * PP + pblk * 128) * DD;
    const __hip_bfloat16* At_g = pt + ((size_t)b * PP + pblk * 128) * DD;
    const __hip_bfloat16* Bh_g = gh + ((size_t)b * TT + tblk * 128) * DD;
    const __hip_bfloat16* Bt_g = gt + ((size_t)b * TT + tblk * 128) * DD;

    // staging: LDS linear tid*16 = row (tid>>2), slot (tid&3).
    // source k-chunk = slot ^ ((row>>1)&3)
    int schunk = (tid & 3) ^ ((tid >> 3) & 3);
    size_t srow = (size_t)(tid >> 2) * DD + schunk * 8;

#define STAGE(c, step)                                                        \
    do {                                                                      \
        size_t ko = srow + (size_t)(step) * BK;                               \
        char* lb = smem + (c) * 32768 + (size_t)tid * 16;                     \
        gload16(Ah_g + ko, lb);                                               \
        gload16(At_g + ko, lb + 8192);                                        \
        gload16(Bh_g + ko, lb + 16384);                                       \
        gload16(Bt_g + ko, lb + 24576);                                       \
    } while (0)

    // per-wave fragment addressing (row pitch 64B, swizzled 16B slot)
    int qi = w & 3, qr = qi >> 1, qc = qi & 1;
    int Aoff = (w < 4) ? 0 : 8192;
    int Boff = (w < 4) ? 16384 : 24576;
    int slot = (lg ^ ((l15 >> 1) & 3)) * 16;
    int oA0 = Aoff + (qr * 64 +  0 + l15) * 64 + slot;
    int oA1 = Aoff + (qr * 64 + 16 + l15) * 64 + slot;
    int oA2 = Aoff + (qr * 64 + 32 + l15) * 64 + slot;
    int oA3 = Aoff + (qr * 64 + 48 + l15) * 64 + slot;
    int oB0 = Boff + (qc * 64 +  0 + l15) * 64 + slot;
    int oB1 = Boff + (qc * 64 + 16 + l15) * 64 + slot;
    int oB2 = Boff + (qc * 64 + 32 + l15) * 64 + slot;
    int oB3 = Boff + (qc * 64 + 48 + l15) * 64 + slot;

    f32x4 c00 = {0.f,0.f,0.f,0.f}, c01 = c00, c02 = c00, c03 = c00;
    f32x4 c10 = c00, c11 = c00, c12 = c00, c13 = c00;
    f32x4 c20 = c00, c21 = c00, c22 = c00, c23 = c00;
    f32x4 c30 = c00, c31 = c00, c32 = c00, c33 = c00;

    int cur = 0;
    STAGE(0, 0);
    __syncthreads();

    for (int t = 0; t < DD / BK; ++t) {
        if (t < DD / BK - 1) STAGE(cur ^ 1, t + 1);
        const char* bp = smem + cur * 32768;
        short8 fa0 = *(const short8*)(bp + oA0);
        short8 fa1 = *(const short8*)(bp + oA1);
        short8 fa2 = *(const short8*)(bp + oA2);
        short8 fa3 = *(const short8*)(bp + oA3);
        short8 fb0 = *(const short8*)(bp + oB0);
        short8 fb1 = *(const short8*)(bp + oB1);
        short8 fb2 = *(const short8*)(bp + oB2);
        short8 fb3 = *(const short8*)(bp + oB3);
        c00 = __builtin_amdgcn_mfma_f32_16x16x32_bf16(fa0, fb0, c00, 0, 0, 0);
        c01 = __builtin_amdgcn_mfma_f32_16x16x32_bf16(fa0, fb1, c01, 0, 0, 0);
        c02 = __builtin_amdgcn_mfma_f32_16x16x32_bf16(fa0, fb2, c02, 0, 0, 0);
        c03 = __builtin_amdgcn_mfma_f32_16x16x32_bf16(fa0, fb3, c03, 0, 0, 0);
        c10 = __builtin_amdgcn_mfma_f32_16x16x32_bf16(fa1, fb0, c10, 0, 0, 0);
        c11 = __builtin_amdgcn_mfma_f32_16x16x32_bf16(fa1, fb1, c11, 0, 0, 0);
        c12 = __builtin_amdgcn_mfma_f32_16x16x32_bf16(fa1, fb2, c12, 0, 0, 0);
        c13 = __builtin_amdgcn_mfma_f32_16x16x32_bf16(fa1, fb3, c13, 0, 0, 0);
        c20 = __builtin_amdgcn_mfma_f32_16x16x32_bf16(fa2, fb0, c20, 0, 0, 0);
        c21 = __builtin_amdgcn_mfma_f32_16x16x32_bf16(fa2, fb1, c21, 0, 0, 0);
        c22 = __builtin_amdgcn_mfma_f32_16x16x32_bf16(fa2, fb2, c22, 0, 0, 0);
        c23 = __builtin_amdgcn_mfma_f32_16x16x32_bf16(fa2, fb3, c23, 0, 0, 0);
        c30 = __builtin_amdgcn_mfma_f32_16x16x32_bf16(fa3, fb0, c30, 0, 0, 0);
        c31 = __builtin_amdgcn_mfma_f32_16x16x32_bf16(fa3, fb1, c31, 0, 0, 0);
        c32 = __builtin_amdgcn_mfma_f32_16x16x32_bf16(fa3, fb2, c32, 0, 0, 0);
        c33 = __builtin_amdgcn_mfma_f32_16x16x32_bf16(fa3, fb3, c33, 0, 0, 0);
        __syncthreads();          // drains vmcnt (next tile landed) + lgkm
        cur ^= 1;
    }
#undef STAGE

    // epilogue: H (waves 0-3) x T (waves 4-7), swizzled quad exchange via LDS.
    float* bwv = (float*)(smem + 16384);          // [128][2]
    int*   bwt = (int*)(smem + 17408);            // [128][2]
    int wp = w & 3;
    char* xrow = smem + (wp * 64 + l) * 64;       // 16KB exchange region
    int qsw = (l >> 1) & 3;

#define XW(q, v) *(f32x4*)(xrow + (((q) ^ qsw) * 16)) = (v)
#define XR(q)    *(const f32x4*)(xrow + (((q) ^ qsw) * 16))

#define ASTEP(ii, jj, rr, TQ)                                                 \
        { float h = c##ii##jj[rr]; float tv = (TQ)[rr];                       \
          bool ok = (h > THRESH) && (tv > THRESH);                            \
          float sc = ok ? 0.5f * (h + tv) : -INFINITY;                        \
          if (sc > bv) { bv = sc; bt = qc * 64 + jj * 16 + l15; } }

#define AMX(ii, rr)                                                           \
    {   float bv = -INFINITY; int bt = 0x7fffffff;                            \
        ASTEP(ii, 0, rr, t0) ASTEP(ii, 1, rr, t1)                             \
        ASTEP(ii, 2, rr, t2) ASTEP(ii, 3, rr, t3)                             \
        for (int m = 1; m < 16; m <<= 1) {                                    \
            float v2 = __shfl_xor(bv, m); int q2 = __shfl_xor(bt, m);         \
            if (v2 > bv || (v2 == bv && q2 < bt)) { bv = v2; bt = q2; }       \
        }                                                                     \
        if (l15 == 0) { int p = qr * 64 + ii * 16 + lg * 4 + rr;              \
            bwv[p * 2 + qc] = bv; bwt[p * 2 + qc] = bt; }                     \
    }

#define EPI(ii)                                                               \
    if (w >= 4) { XW(0, c##ii##0); XW(1, c##ii##1);                           \
                  XW(2, c##ii##2); XW(3, c##ii##3); }                         \
    __syncthreads();                                                          \
    if (w < 4) {                                                              \
        f32x4 t0 = XR(0), t1 = XR(1), t2 = XR(2), t3 = XR(3);                 \
        AMX(ii, 0) AMX(ii, 1) AMX(ii, 2) AMX(ii, 3)                           \
    }                                                                         \
    __syncthreads();

    EPI(0)
    EPI(1)
    EPI(2)
    EPI(3)
#undef EPI
#undef AMX
#undef ASTEP
#undef XW
#undef XR

    if (tid < 128) {
        float v = bwv[tid * 2 + 0]; int t1 = bwt[tid * 2 + 0];
        float v2 = bwv[tid * 2 + 1]; int t2 = bwt[tid * 2 + 1];
        if (v2 > v || (v2 == v && t2 < t1)) { v = v2; t1 = t2; }
        int grow = b * PP + pblk * 128 + tid;
        cand_v[(size_t)grow * 4 + tblk] = v;
        cand_t[(size_t)grow * 4 + tblk] = (v > -INFINITY) ? (tblk * 128 + t1) : 0x7fffffff;
    }
}

// ---------------- stage 2b: merge 4 t-blocks -> target class -----------------
__global__ void merge_kernel(const float* __restrict__ cand_v,
                             const int* __restrict__ cand_t,
                             const int* __restrict__ rel,
                             int* __restrict__ tgt) {
    int row = blockIdx.x * 256 + threadIdx.x;    // B*P rows
    float v = -INFINITY; int t = 0x7fffffff;
#pragma unroll
    for (int k = 0; k < 4; ++k) {
        float v2 = cand_v[(size_t)row * 4 + k];
        int t2 = cand_t[(size_t)row * 4 + k];
        if (v2 > v || (v2 == v && t2 < t)) { v = v2; t = t2; }
    }
    int b = row >> 9;
    tgt[row] = (v > -INFINITY) ? rel[b * TT + t] : 0;
}

// ---------------- stage 3: per-row NLL from log-softmax ----------------------
__global__ void nll_kernel(const float* __restrict__ preds,
                           const int* __restrict__ tgt,
                           float* __restrict__ partials) {
    int w = threadIdx.x >> 6, l = threadIdx.x & 63;
    int row = blockIdx.x * 4 + w;
    const float* x = preds + (size_t)row * CC;

    float a = x[l];
    float b2 = (l + 64 < CC) ? x[l + 64] : -INFINITY;
    float mx = fmaxf(a, b2);
    for (int m = 32; m; m >>= 1) mx = fmaxf(mx, __shfl_xor(mx, m));
    float e = __expf(a - mx) + ((l + 64 < CC) ? __expf(b2 - mx) : 0.0f);
    for (int m = 32; m; m >>= 1) e += __shfl_xor(e, m);

    __shared__ float part[4];
    if (l == 0) {
        int tg = tgt[row];
        part[w] = mx + logf(e) - x[tg];
    }
    __syncthreads();
    if (threadIdx.x == 0)
        partials[blockIdx.x] = part[0] + part[1] + part[2] + part[3];
}

// ---------------- stage 4: final mean ----------------------------------------
__global__ void final_reduce_kernel(const float* __restrict__ partials, int n,
                                    float* __restrict__ out) {
    float s = 0.f;
    for (int i = threadIdx.x; i < n; i += 256) s += partials[i];
    for (int m = 32; m; m >>= 1) s += __shfl_xor(s, m);
    __shared__ float ps[4];
    if ((threadIdx.x & 63) == 0) ps[threadIdx.x >> 6] = s;
    __syncthreads();
    if (threadIdx.x == 0)
        out[0] = (ps[0] + ps[1] + ps[2] + ps[3]) / (float)(BB * PP);
}

extern "C" void kernel_launch(void* const* d_in, const int* in_sizes, int n_in,
                              void* d_out, int out_size, void* d_ws, size_t ws_size,
                              hipStream_t stream) {
    const float* pairs = (const float*)d_in[0];  // [B,P,1536]
    const float* preds = (const float*)d_in[1];  // [B,P,97]
    const float* trip  = (const float*)d_in[2];  // [B,T,1537]
    float* out = (float*)d_out;

    char* ws = (char*)d_ws;
    size_t vec_bytes = (size_t)BB * PP * DD * sizeof(__hip_bfloat16);  // 25,165,824
    __hip_bfloat16* ph = (__hip_bfloat16*)(ws);
    __hip_bfloat16* pt = (__hip_bfloat16*)(ws + vec_bytes);
    __hip_bfloat16* gh = (__hip_bfloat16*)(ws + 2 * vec_bytes);
    __hip_bfloat16* gt = (__hip_bfloat16*)(ws + 3 * vec_bytes);
    char* p = ws + 4 * vec_bytes;
    int* rel = (int*)p;              p += (size_t)BB * TT * sizeof(int);        // 64KB
    int* tgt = (int*)p;              p += (size_t)BB * PP * sizeof(int);        // 64KB
    float* cand_v = (float*)p;       p += (size_t)BB * PP * 4 * sizeof(float);  // 256KB
    int* cand_t = (int*)p;           p += (size_t)BB * PP * 4 * sizeof(int);    // 256KB
    float* partials = (float*)p;                                                // 16KB

    norm_pairs_kernel<<<BB * PP, 256, 0, stream>>>(pairs, ph, pt);
    norm_trip_kernel<<<BB * TT, 256, 0, stream>>>(trip, gh, gt, rel);
    match_kernel<<<BB * 16, 512, 0, stream>>>(ph, pt, gh, gt, cand_v, cand_t);
    merge_kernel<<<BB * PP / 256, 256, 0, stream>>>(cand_v, cand_t, rel, tgt);
    nll_kernel<<<BB * PP / 4, 256, 0, stream>>>(preds, tgt, partials);
    final_reduce_kernel<<<1, 256, 0, stream>>>(partials, BB * PP / 4, out);
}

// Round 8
// 107.790 us; speedup vs baseline: 3.6347x; 1.1657x over previous
//
#include <hip/hip_runtime.h>
#include <hip/hip_bf16.h>
#include <math.h>

#define DD 768
#define BB 32
#define PP 512
#define TT 512
#define CC 97
#define THRESH 0.8f
#define BK 32

typedef __attribute__((ext_vector_type(8))) short short8;
typedef __attribute__((ext_vector_type(4))) float f32x4;
typedef float4 f4u __attribute__((aligned(4)));

__device__ __forceinline__ void gload16(const void* g, void* l) {
    __builtin_amdgcn_global_load_lds(
        (const __attribute__((address_space(1))) unsigned int*)g,
        (__attribute__((address_space(3))) unsigned int*)l, 16, 0, 0);
}

__device__ __forceinline__ ushort4 pack4(float4 v, float s) {
    __hip_bfloat16 a = __float2bfloat16(v.x * s), b = __float2bfloat16(v.y * s),
                   c = __float2bfloat16(v.z * s), d = __float2bfloat16(v.w * s);
    ushort4 o;
    o.x = *(unsigned short*)&a; o.y = *(unsigned short*)&b;
    o.z = *(unsigned short*)&c; o.w = *(unsigned short*)&d;
    return o;
}

// ---------------- stage 1a: normalize entity pairs (float4 vectorized) -------
__global__ void norm_pairs_kernel(const float* __restrict__ pairs,
                                  __hip_bfloat16* __restrict__ ph,
                                  __hip_bfloat16* __restrict__ pt) {
    int row = blockIdx.x;            // B*P rows
    int t = threadIdx.x;             // 256 threads
    const float4* s4 = (const float4*)(pairs + (size_t)row * (2 * DD));
    float4 v0 = s4[t];
    float4 v1 = make_float4(0.f, 0.f, 0.f, 0.f);
    if (t < 128) v1 = s4[256 + t];
    float d0 = v0.x * v0.x + v0.y * v0.y + v0.z * v0.z + v0.w * v0.w;
    float d1 = v1.x * v1.x + v1.y * v1.y + v1.z * v1.z + v1.w * v1.w;
    float sh = (t < 192) ? d0 : 0.f;
    float st = ((t >= 192) ? d0 : 0.f) + d1;

    for (int off = 32; off; off >>= 1) {
        sh += __shfl_down(sh, off);
        st += __shfl_down(st, off);
    }
    __shared__ float red[2][5];
    int wid = t >> 6, lane = t & 63;
    if (lane == 0) { red[0][wid] = sh; red[1][wid] = st; }
    __syncthreads();
    if (t == 0) {
        float a = red[0][0] + red[0][1] + red[0][2] + red[0][3];
        float b = red[1][0] + red[1][1] + red[1][2] + red[1][3];
        red[0][4] = 1.0f / fmaxf(sqrtf(a), 1e-8f);
        red[1][4] = 1.0f / fmaxf(sqrtf(b), 1e-8f);
    }
    __syncthreads();
    float ih = red[0][4], it = red[1][4];
    ushort4* dh = (ushort4*)(ph + (size_t)row * DD);
    ushort4* dt = (ushort4*)(pt + (size_t)row * DD);
    ushort4 o0 = pack4(v0, (t < 192) ? ih : it);
    if (t < 192) dh[t] = o0; else dt[t - 192] = o0;
    if (t < 128) dt[t + 64] = pack4(v1, it);
}

// ---------------- stage 1b: normalize triplets (vectorized, 4B-aligned x4) ---
// row = 1537 floats. head = f4 chunks of cols [0,768) from row base; tail =
// f4 chunks of cols [769,1537) re-based at col 769 (so gt stores align).
// Thread t: loadA = t<192 ? head[t] : tail[t-192]; loadB (t<128) = tail[64+t].
__global__ void norm_trip_kernel(const float* __restrict__ trip,
                                 __hip_bfloat16* __restrict__ gh,
                                 __hip_bfloat16* __restrict__ gt,
                                 int* __restrict__ rel) {
    int row = blockIdx.x;            // B*T rows
    int t = threadIdx.x;             // 256 threads
    const float* src = trip + (size_t)row * (2 * DD + 1);
    const f4u* hp = (const f4u*)src;
    const f4u* tp = (const f4u*)(src + DD + 1);

    float4 A = (t < 192) ? (float4)hp[t] : (float4)tp[t - 192];
    float4 Bv = make_float4(0.f, 0.f, 0.f, 0.f);
    if (t < 128) Bv = tp[64 + t];
    float dA = A.x * A.x + A.y * A.y + A.z * A.z + A.w * A.w;
    float dB = Bv.x * Bv.x + Bv.y * Bv.y + Bv.z * Bv.z + Bv.w * Bv.w;
    float sh = (t < 192) ? dA : 0.f;
    float st = ((t >= 192) ? dA : 0.f) + dB;

    for (int off = 32; off; off >>= 1) {
        sh += __shfl_down(sh, off);
        st += __shfl_down(st, off);
    }
    __shared__ float red[2][5];
    int wid = t >> 6, lane = t & 63;
    if (lane == 0) { red[0][wid] = sh; red[1][wid] = st; }
    __syncthreads();
    if (t == 0) {
        float a = red[0][0] + red[0][1] + red[0][2] + red[0][3];
        float b = red[1][0] + red[1][1] + red[1][2] + red[1][3];
        red[0][4] = 1.0f / fmaxf(sqrtf(a), 1e-8f);
        red[1][4] = 1.0f / fmaxf(sqrtf(b), 1e-8f);
        rel[row] = (int)src[DD];
    }
    __syncthreads();
    float ih = red[0][4], it = red[1][4];
    ushort4* dh = (ushort4*)(gh + (size_t)row * DD);
    ushort4* dt = (ushort4*)(gt + (size_t)row * DD);
    ushort4 oA = pack4(A, (t < 192) ? ih : it);
    if (t < 192) dh[t] = oA; else dt[t - 192] = oA;
    if (t < 128) dt[64 + t] = pack4(Bv, it);
}

// ---------------- stage 2: 3-buffer counted-vmcnt dual-GEMM ------------------
// Block: 512 thr = 8 waves, tile 256p x 128t of one batch, 1 block/CU (144KB).
// Waves 0-3: H array, waves 4-7: T array; wave w owns rows (w&3)*64..+64, all
// 128 t-cols (4x8 fragment grid: 12 ds_reads / 32 MFMAs per BK=32 step).
// Pipeline: STAGE(t+2) -> s_waitcnt vmcnt(12) -> s_barrier -> compute(t) ->
// s_barrier. Loads rest 2 full iterations before use; NEVER vmcnt(0) in loop.
// LDS slot swizzle (both-sides): chunk c of row r at phys slot c^((r>>1)&3).
__global__ __launch_bounds__(512, 2) void match_kernel(
        const __hip_bfloat16* __restrict__ ph, const __hip_bfloat16* __restrict__ pt,
        const __hip_bfloat16* __restrict__ gh, const __hip_bfloat16* __restrict__ gt,
        float* __restrict__ cand_v, int* __restrict__ cand_t) {
    __shared__ __align__(16) char smem[147456];   // 3 x 48KB (Ah16|At16|Bh8|Bt8)

    // XCD swizzle (256 blocks, %8==0 -> bijective)
    int bid = blockIdx.x;
    int swz = (bid & 7) * 32 + (bid >> 3);
    int b = swz >> 3, sub = swz & 7;
    int pblk = sub >> 2, tblk = sub & 3;          // 2 p-blocks x 4 t-blocks

    int tid = threadIdx.x;
    int w = tid >> 6, l = tid & 63;
    int l15 = l & 15, lg = l >> 4;

    const __hip_bfloat16* Ah_g = ph + ((size_t)b * PP + pblk * 256) * DD;
    const __hip_bfloat16* At_g = pt + ((size_t)b * PP + pblk * 256) * DD;
    const __hip_bfloat16* Bh_g = gh + ((size_t)b * TT + tblk * 128) * DD;
    const __hip_bfloat16* Bt_g = gt + ((size_t)b * TT + tblk * 128) * DD;

    // staging slots r=0..5: seg s = tid+512r (768 segs of 64B), dest = s*16.
    auto srcp = [&](int r) {
        int s = tid + 512 * r, seg = s >> 2, ln = s & 3;
        const __hip_bfloat16* bp; int ro;
        if (seg < 256)      { bp = Ah_g; ro = seg; }
        else if (seg < 512) { bp = At_g; ro = seg - 256; }
        else if (seg < 640) { bp = Bh_g; ro = seg - 512; }
        else                { bp = Bt_g; ro = seg - 640; }
        return bp + (size_t)ro * DD + (ln ^ ((ro >> 1) & 3)) * 8;
    };
    const __hip_bfloat16* sp0 = srcp(0);
    const __hip_bfloat16* sp1 = srcp(1);
    const __hip_bfloat16* sp2 = srcp(2);
    const __hip_bfloat16* sp3 = srcp(3);
    const __hip_bfloat16* sp4 = srcp(4);
    const __hip_bfloat16* sp5 = srcp(5);

#define STAGE(bufb, step)                                                     \
    do {                                                                      \
        size_t ko = (size_t)(step) * BK;                                      \
        char* lb = smem + (bufb) + (size_t)tid * 16;                          \
        gload16(sp0 + ko, lb);                                                \
        gload16(sp1 + ko, lb + 8192);                                         \
        gload16(sp2 + ko, lb + 16384);                                        \
        gload16(sp3 + ko, lb + 24576);                                        \
        gload16(sp4 + ko, lb + 32768);                                        \
        gload16(sp5 + ko, lb + 40960);                                        \
    } while (0)

    // read addressing: row pitch 64B; phys slot = lg ^ ((l15>>1)&3)
    int qr = w & 3;
    int Aoff = (w < 4) ? 0 : 16384;
    int Boff = (w < 4) ? 32768 : 40960;
    int slot = (lg ^ ((l15 >> 1) & 3)) * 16;
    int Abase = Aoff + (qr * 64 + l15) * 64 + slot;   // +i*1024
    int Bbase = Boff + l15 * 64 + slot;               // +j*1024

    f32x4 z = {0.f, 0.f, 0.f, 0.f};
    f32x4 a00=z,a01=z,a02=z,a03=z,a04=z,a05=z,a06=z,a07=z;
    f32x4 a10=z,a11=z,a12=z,a13=z,a14=z,a15=z,a16=z,a17=z;
    f32x4 a20=z,a21=z,a22=z,a23=z,a24=z,a25=z,a26=z,a27=z;
    f32x4 a30=z,a31=z,a32=z,a33=z,a34=z,a35=z,a36=z,a37=z;

#define MM(i, j, fa, fb) a##i##j = __builtin_amdgcn_mfma_f32_16x16x32_bf16(fa, fb, a##i##j, 0, 0, 0)
#define COMPUTE(bufb)                                                         \
    do {                                                                      \
        const char* bp = smem + (bufb);                                       \
        short8 fa0 = *(const short8*)(bp + Abase + 0);                        \
        short8 fa1 = *(const short8*)(bp + Abase + 1024);                     \
        short8 fa2 = *(const short8*)(bp + Abase + 2048);                     \
        short8 fa3 = *(const short8*)(bp + Abase + 3072);                     \
        short8 g0 = *(const short8*)(bp + Bbase + 0);                         \
        short8 g1 = *(const short8*)(bp + Bbase + 1024);                      \
        short8 g2 = *(const short8*)(bp + Bbase + 2048);                      \
        short8 g3 = *(const short8*)(bp + Bbase + 3072);                      \
        MM(0,0,fa0,g0); MM(1,0,fa1,g0); MM(2,0,fa2,g0); MM(3,0,fa3,g0);       \
        MM(0,1,fa0,g1); MM(1,1,fa1,g1); MM(2,1,fa2,g1); MM(3,1,fa3,g1);       \
        MM(0,2,fa0,g2); MM(1,2,fa1,g2); MM(2,2,fa2,g2); MM(3,2,fa3,g2);       \
        MM(0,3,fa0,g3); MM(1,3,fa1,g3); MM(2,3,fa2,g3); MM(3,3,fa3,g3);       \
        g0 = *(const short8*)(bp + Bbase + 4096);                             \
        g1 = *(const short8*)(bp + Bbase + 5120);                             \
        g2 = *(const short8*)(bp + Bbase + 6144);                             \
        g3 = *(const short8*)(bp + Bbase + 7168);                             \
        MM(0,4,fa0,g0); MM(1,4,fa1,g0); MM(2,4,fa2,g0); MM(3,4,fa3,g0);       \
        MM(0,5,fa0,g1); MM(1,5,fa1,g1); MM(2,5,fa2,g1); MM(3,5,fa3,g1);       \
        MM(0,6,fa0,g2); MM(1,6,fa1,g2); MM(2,6,fa2,g2); MM(3,6,fa3,g2);       \
        MM(0,7,fa0,g3); MM(1,7,fa1,g3); MM(2,7,fa2,g3); MM(3,7,fa3,g3);       \
    } while (0)

    STAGE(0, 0);
    STAGE(49152, 1);
    for (int t = 0; t < 22; ++t) {
        STAGE(((t + 2) % 3) * 49152, t + 2);
        asm volatile("s_waitcnt vmcnt(12)" ::: "memory");
        __builtin_amdgcn_s_barrier();
        asm volatile("" ::: "memory");
        COMPUTE((t % 3) * 49152);
        asm volatile("" ::: "memory");
        __builtin_amdgcn_s_barrier();
    }
    asm volatile("s_waitcnt vmcnt(6)" ::: "memory");
    __builtin_amdgcn_s_barrier();
    asm volatile("" ::: "memory");
    COMPUTE(49152);                      // t = 22 (buf 1)
    asm volatile("" ::: "memory");
    __builtin_amdgcn_s_barrier();
    asm volatile("s_waitcnt vmcnt(0)" ::: "memory");
    __builtin_amdgcn_s_barrier();
    asm volatile("" ::: "memory");
    COMPUTE(98304);                      // t = 23 (buf 2)
#undef COMPUTE
#undef MM
#undef STAGE

    __syncthreads();
    // epilogue: H-wave wp combines with T-wave wp via swizzled LDS exchange.
    float* bwv = (float*)(smem + 32768);          // [256]
    int*   bwt = (int*)(smem + 33792);            // [256]
    int wp = w & 3;
    char* xrow = smem + (wp * 64 + l) * 128;      // 32KB exchange region
    int qsw = l & 7;

#define XW(q, v) *(f32x4*)(xrow + (((q) ^ qsw) * 16)) = (v)
#define XR(q)    *(const f32x4*)(xrow + (((q) ^ qsw) * 16))

#define ASTEP(ii, jj, rr, TQ)                                                 \
        { float h = a##ii##jj[rr]; float tv = (TQ)[rr];                       \
          bool ok = (h > THRESH) && (tv > THRESH);                            \
          float sc = ok ? 0.5f * (h + tv) : -INFINITY;                        \
          if (sc > bv) { bv = sc; bt = jj * 16 + l15; } }

#define AMX(ii, rr)                                                           \
    {   float bv = -INFINITY; int bt = 0x7fffffff;                            \
        ASTEP(ii, 0, rr, t0) ASTEP(ii, 1, rr, t1)                             \
        ASTEP(ii, 2, rr, t2) ASTEP(ii, 3, rr, t3)                             \
        ASTEP(ii, 4, rr, t4) ASTEP(ii, 5, rr, t5)                             \
        ASTEP(ii, 6, rr, t6) ASTEP(ii, 7, rr, t7)                             \
        for (int m = 1; m < 16; m <<= 1) {                                    \
            float v2 = __shfl_xor(bv, m); int q2 = __shfl_xor(bt, m);         \
            if (v2 > bv || (v2 == bv && q2 < bt)) { bv = v2; bt = q2; }       \
        }                                                                     \
        if (l15 == 0) { int p = qr * 64 + ii * 16 + lg * 4 + rr;              \
            bwv[p] = bv; bwt[p] = bt; }                                       \
    }

#define EPI(ii)                                                               \
    if (w >= 4) { XW(0, a##ii##0); XW(1, a##ii##1); XW(2, a##ii##2);          \
                  XW(3, a##ii##3); XW(4, a##ii##4); XW(5, a##ii##5);          \
                  XW(6, a##ii##6); XW(7, a##ii##7); }                         \
    __syncthreads();                                                          \
    if (w < 4) {                                                              \
        f32x4 t0 = XR(0), t1 = XR(1), t2 = XR(2), t3 = XR(3);                 \
        f32x4 t4 = XR(4), t5 = XR(5), t6 = XR(6), t7 = XR(7);                 \
        AMX(ii, 0) AMX(ii, 1) AMX(ii, 2) AMX(ii, 3)                           \
    }                                                                         \
    __syncthreads();

    EPI(0)
    EPI(1)
    EPI(2)
    EPI(3)
#undef EPI
#undef AMX
#undef ASTEP
#undef XW
#undef XR

    if (tid < 256) {
        float v = bwv[tid]; int t1 = bwt[tid];
        int grow = b * PP + pblk * 256 + tid;
        cand_v[(size_t)grow * 4 + tblk] = v;
        cand_t[(size_t)grow * 4 + tblk] = (v > -INFINITY) ? (tblk * 128 + t1) : 0x7fffffff;
    }
}

// ---------------- stage 2b: merge 4 t-blocks -> target class -----------------
__global__ void merge_kernel(const float* __restrict__ cand_v,
                             const int* __restrict__ cand_t,
                             const int* __restrict__ rel,
                             int* __restrict__ tgt) {
    int row = blockIdx.x * 256 + threadIdx.x;    // B*P rows
    float v = -INFINITY; int t = 0x7fffffff;
#pragma unroll
    for (int k = 0; k < 4; ++k) {
        float v2 = cand_v[(size_t)row * 4 + k];
        int t2 = cand_t[(size_t)row * 4 + k];
        if (v2 > v || (v2 == v && t2 < t)) { v = v2; t = t2; }
    }
    int b = row >> 9;
    tgt[row] = (v > -INFINITY) ? rel[b * TT + t] : 0;
}

// ---------------- stage 3: per-row NLL from log-softmax ----------------------
__global__ void nll_kernel(const float* __restrict__ preds,
                           const int* __restrict__ tgt,
                           float* __restrict__ partials) {
    int w = threadIdx.x >> 6, l = threadIdx.x & 63;
    int row = blockIdx.x * 4 + w;
    const float* x = preds + (size_t)row * CC;

    float a = x[l];
    float b2 = (l + 64 < CC) ? x[l + 64] : -INFINITY;
    float mx = fmaxf(a, b2);
    for (int m = 32; m; m >>= 1) mx = fmaxf(mx, __shfl_xor(mx, m));
    float e = __expf(a - mx) + ((l + 64 < CC) ? __expf(b2 - mx) : 0.0f);
    for (int m = 32; m; m >>= 1) e += __shfl_xor(e, m);

    __shared__ float part[4];
    if (l == 0) {
        int tg = tgt[row];
        part[w] = mx + logf(e) - x[tg];
    }
    __syncthreads();
    if (threadIdx.x == 0)
        partials[blockIdx.x] = part[0] + part[1] + part[2] + part[3];
}

// ---------------- stage 4: final mean ----------------------------------------
__global__ void final_reduce_kernel(const float* __restrict__ partials, int n,
                                    float* __restrict__ out) {
    float s = 0.f;
    for (int i = threadIdx.x; i < n; i += 256) s += partials[i];
    for (int m = 32; m; m >>= 1) s += __shfl_xor(s, m);
    __shared__ float ps[4];
    if ((threadIdx.x & 63) == 0) ps[threadIdx.x >> 6] = s;
    __syncthreads();
    if (threadIdx.x == 0)
        out[0] = (ps[0] + ps[1] + ps[2] + ps[3]) / (float)(BB * PP);
}

extern "C" void kernel_launch(void* const* d_in, const int* in_sizes, int n_in,
                              void* d_out, int out_size, void* d_ws, size_t ws_size,
                              hipStream_t stream) {
    const float* pairs = (const float*)d_in[0];  // [B,P,1536]
    const float* preds = (const float*)d_in[1];  // [B,P,97]
    const float* trip  = (const float*)d_in[2];  // [B,T,1537]
    float* out = (float*)d_out;

    char* ws = (char*)d_ws;
    size_t vec_bytes = (size_t)BB * PP * DD * sizeof(__hip_bfloat16);  // 25,165,824
    __hip_bfloat16* ph = (__hip_bfloat16*)(ws);
    __hip_bfloat16* pt = (__hip_bfloat16*)(ws + vec_bytes);
    __hip_bfloat16* gh = (__hip_bfloat16*)(ws + 2 * vec_bytes);
    __hip_bfloat16* gt = (__hip_bfloat16*)(ws + 3 * vec_bytes);
    char* p = ws + 4 * vec_bytes;
    int* rel = (int*)p;              p += (size_t)BB * TT * sizeof(int);        // 64KB
    int* tgt = (int*)p;              p += (size_t)BB * PP * sizeof(int);        // 64KB
    float* cand_v = (float*)p;       p += (size_t)BB * PP * 4 * sizeof(float);  // 256KB
    int* cand_t = (int*)p;           p += (size_t)BB * PP * 4 * sizeof(int);    // 256KB
    float* partials = (float*)p;                                                // 16KB

    norm_pairs_kernel<<<BB * PP, 256, 0, stream>>>(pairs, ph, pt);
    norm_trip_kernel<<<BB * TT, 256, 0, stream>>>(trip, gh, gt, rel);
    match_kernel<<<BB * 8, 512, 0, stream>>>(ph, pt, gh, gt, cand_v, cand_t);
    merge_kernel<<<BB * PP / 256, 256, 0, stream>>>(cand_v, cand_t, rel, tgt);
    nll_kernel<<<BB * PP / 4, 256, 0, stream>>>(preds, tgt, partials);
    final_reduce_kernel<<<1, 256, 0, stream>>>(partials, BB * PP / 4, out);
}

// Round 9
// 105.634 us; speedup vs baseline: 3.7089x; 1.0204x over previous
//
#include <hip/hip_runtime.h>
#include <hip/hip_bf16.h>
#include <math.h>

#define DD 768
#define BB 32
#define PP 512
#define TT 512
#define CC 97
#define THRESH 0.8f
#define BK 32

typedef __attribute__((ext_vector_type(8))) short short8;
typedef __attribute__((ext_vector_type(4))) float f32x4;
typedef float4 f4u __attribute__((aligned(4)));

__device__ __forceinline__ void gload16(const void* g, void* l) {
    __builtin_amdgcn_global_load_lds(
        (const __attribute__((address_space(1))) unsigned int*)g,
        (__attribute__((address_space(3))) unsigned int*)l, 16, 0, 0);
}

__device__ __forceinline__ ushort4 pack4(float4 v, float s) {
    __hip_bfloat16 a = __float2bfloat16(v.x * s), b = __float2bfloat16(v.y * s),
                   c = __float2bfloat16(v.z * s), d = __float2bfloat16(v.w * s);
    ushort4 o;
    o.x = *(unsigned short*)&a; o.y = *(unsigned short*)&b;
    o.z = *(unsigned short*)&c; o.w = *(unsigned short*)&d;
    return o;
}

// ---------------- stage 1a: normalize entity pairs (float4 vectorized) -------
__global__ void norm_pairs_kernel(const float* __restrict__ pairs,
                                  __hip_bfloat16* __restrict__ ph,
                                  __hip_bfloat16* __restrict__ pt) {
    int row = blockIdx.x;            // B*P rows
    int t = threadIdx.x;             // 256 threads
    const float4* s4 = (const float4*)(pairs + (size_t)row * (2 * DD));
    float4 v0 = s4[t];
    float4 v1 = make_float4(0.f, 0.f, 0.f, 0.f);
    if (t < 128) v1 = s4[256 + t];
    float d0 = v0.x * v0.x + v0.y * v0.y + v0.z * v0.z + v0.w * v0.w;
    float d1 = v1.x * v1.x + v1.y * v1.y + v1.z * v1.z + v1.w * v1.w;
    float sh = (t < 192) ? d0 : 0.f;
    float st = ((t >= 192) ? d0 : 0.f) + d1;

    for (int off = 32; off; off >>= 1) {
        sh += __shfl_down(sh, off);
        st += __shfl_down(st, off);
    }
    __shared__ float red[2][5];
    int wid = t >> 6, lane = t & 63;
    if (lane == 0) { red[0][wid] = sh; red[1][wid] = st; }
    __syncthreads();
    if (t == 0) {
        float a = red[0][0] + red[0][1] + red[0][2] + red[0][3];
        float b = red[1][0] + red[1][1] + red[1][2] + red[1][3];
        red[0][4] = 1.0f / fmaxf(sqrtf(a), 1e-8f);
        red[1][4] = 1.0f / fmaxf(sqrtf(b), 1e-8f);
    }
    __syncthreads();
    float ih = red[0][4], it = red[1][4];
    ushort4* dh = (ushort4*)(ph + (size_t)row * DD);
    ushort4* dt = (ushort4*)(pt + (size_t)row * DD);
    ushort4 o0 = pack4(v0, (t < 192) ? ih : it);
    if (t < 192) dh[t] = o0; else dt[t - 192] = o0;
    if (t < 128) dt[t + 64] = pack4(v1, it);
}

// ---------------- stage 1b: normalize triplets (vectorized, 4B-aligned x4) ---
__global__ void norm_trip_kernel(const float* __restrict__ trip,
                                 __hip_bfloat16* __restrict__ gh,
                                 __hip_bfloat16* __restrict__ gt,
                                 int* __restrict__ rel) {
    int row = blockIdx.x;            // B*T rows
    int t = threadIdx.x;             // 256 threads
    const float* src = trip + (size_t)row * (2 * DD + 1);
    const f4u* hp = (const f4u*)src;
    const f4u* tp = (const f4u*)(src + DD + 1);

    float4 A = (t < 192) ? (float4)hp[t] : (float4)tp[t - 192];
    float4 Bv = make_float4(0.f, 0.f, 0.f, 0.f);
    if (t < 128) Bv = tp[64 + t];
    float dA = A.x * A.x + A.y * A.y + A.z * A.z + A.w * A.w;
    float dB = Bv.x * Bv.x + Bv.y * Bv.y + Bv.z * Bv.z + Bv.w * Bv.w;
    float sh = (t < 192) ? dA : 0.f;
    float st = ((t >= 192) ? dA : 0.f) + dB;

    for (int off = 32; off; off >>= 1) {
        sh += __shfl_down(sh, off);
        st += __shfl_down(st, off);
    }
    __shared__ float red[2][5];
    int wid = t >> 6, lane = t & 63;
    if (lane == 0) { red[0][wid] = sh; red[1][wid] = st; }
    __syncthreads();
    if (t == 0) {
        float a = red[0][0] + red[0][1] + red[0][2] + red[0][3];
        float b = red[1][0] + red[1][1] + red[1][2] + red[1][3];
        red[0][4] = 1.0f / fmaxf(sqrtf(a), 1e-8f);
        red[1][4] = 1.0f / fmaxf(sqrtf(b), 1e-8f);
        rel[row] = (int)src[DD];
    }
    __syncthreads();
    float ih = red[0][4], it = red[1][4];
    ushort4* dh = (ushort4*)(gh + (size_t)row * DD);
    ushort4* dt = (ushort4*)(gt + (size_t)row * DD);
    ushort4 oA = pack4(A, (t < 192) ? ih : it);
    if (t < 192) dh[t] = oA; else dt[t - 192] = oA;
    if (t < 128) dt[64 + t] = pack4(Bv, it);
}

// ---------------- stage 2: 3-buffer, 4-phase counted-vmcnt dual-GEMM ---------
// R8 skeleton (3x48KB bufs, 2-deep prefetch, slot swizzle, H/T wave split) +
// R9 phase-split: each K-step = 4 phases {ds_read subtile | part of
// STAGE(t+2) -> s_barrier -> setprio(1) 8xMFMA setprio(0) -> s_barrier}.
// vmcnt(6) once at step entry (stages issue AFTER the wait -> 6 not 12).
__global__ __launch_bounds__(512, 2) void match_kernel(
        const __hip_bfloat16* __restrict__ ph, const __hip_bfloat16* __restrict__ pt,
        const __hip_bfloat16* __restrict__ gh, const __hip_bfloat16* __restrict__ gt,
        float* __restrict__ cand_v, int* __restrict__ cand_t) {
    __shared__ __align__(16) char smem[147456];   // 3 x 48KB (Ah16|At16|Bh8|Bt8)

    // XCD swizzle (256 blocks, %8==0 -> bijective)
    int bid = blockIdx.x;
    int swz = (bid & 7) * 32 + (bid >> 3);
    int b = swz >> 3, sub = swz & 7;
    int pblk = sub >> 2, tblk = sub & 3;          // 2 p-blocks x 4 t-blocks

    int tid = threadIdx.x;
    int w = tid >> 6, l = tid & 63;
    int l15 = l & 15, lg = l >> 4;

    const __hip_bfloat16* Ah_g = ph + ((size_t)b * PP + pblk * 256) * DD;
    const __hip_bfloat16* At_g = pt + ((size_t)b * PP + pblk * 256) * DD;
    const __hip_bfloat16* Bh_g = gh + ((size_t)b * TT + tblk * 128) * DD;
    const __hip_bfloat16* Bt_g = gt + ((size_t)b * TT + tblk * 128) * DD;

    // staging slots r=0..5: seg s = tid+512r (768 segs of 64B), dest = s*16.
    auto srcp = [&](int r) {
        int s = tid + 512 * r, seg = s >> 2, ln = s & 3;
        const __hip_bfloat16* bp; int ro;
        if (seg < 256)      { bp = Ah_g; ro = seg; }
        else if (seg < 512) { bp = At_g; ro = seg - 256; }
        else if (seg < 640) { bp = Bh_g; ro = seg - 512; }
        else                { bp = Bt_g; ro = seg - 640; }
        return bp + (size_t)ro * DD + (ln ^ ((ro >> 1) & 3)) * 8;
    };
    const __hip_bfloat16* sp0 = srcp(0);
    const __hip_bfloat16* sp1 = srcp(1);
    const __hip_bfloat16* sp2 = srcp(2);
    const __hip_bfloat16* sp3 = srcp(3);
    const __hip_bfloat16* sp4 = srcp(4);
    const __hip_bfloat16* sp5 = srcp(5);

    // read addressing: row pitch 64B; phys slot = lg ^ ((l15>>1)&3)
    int qr = w & 3;
    int Aoff = (w < 4) ? 0 : 16384;
    int Boff = (w < 4) ? 32768 : 40960;
    int slot = (lg ^ ((l15 >> 1) & 3)) * 16;
    int Abase = Aoff + (qr * 64 + l15) * 64 + slot;   // +i*1024
    int Bbase = Boff + l15 * 64 + slot;               // +j*1024

    f32x4 z = {0.f, 0.f, 0.f, 0.f};
    f32x4 a00=z,a01=z,a02=z,a03=z,a04=z,a05=z,a06=z,a07=z;
    f32x4 a10=z,a11=z,a12=z,a13=z,a14=z,a15=z,a16=z,a17=z;
    f32x4 a20=z,a21=z,a22=z,a23=z,a24=z,a25=z,a26=z,a27=z;
    f32x4 a30=z,a31=z,a32=z,a33=z,a34=z,a35=z,a36=z,a37=z;

#define MM(i, j, fa, fb) a##i##j = __builtin_amdgcn_mfma_f32_16x16x32_bf16(fa, fb, a##i##j, 0, 0, 0)
#define BAR __builtin_amdgcn_s_barrier()

// one K-step as 4 phases. STG(n): stage gload n into buffer nbuf for step t+2
// (expands empty for tail steps).
#define STEP(cbuf, S0, S1, S2, S3, S4, S5, VMSTR)                             \
    do {                                                                      \
        const char* bp = smem + (cbuf);                                       \
        asm volatile("s_waitcnt vmcnt(" VMSTR ")" ::: "memory");              \
        /* ph1 */                                                             \
        short8 fa0 = *(const short8*)(bp + Abase + 0);                        \
        short8 fa1 = *(const short8*)(bp + Abase + 1024);                     \
        short8 fa2 = *(const short8*)(bp + Abase + 2048);                     \
        short8 fa3 = *(const short8*)(bp + Abase + 3072);                     \
        short8 g0 = *(const short8*)(bp + Bbase + 0);                         \
        short8 g1 = *(const short8*)(bp + Bbase + 1024);                      \
        S0; S1;                                                               \
        BAR;                                                                  \
        __builtin_amdgcn_s_setprio(1);                                        \
        MM(0,0,fa0,g0); MM(1,0,fa1,g0); MM(2,0,fa2,g0); MM(3,0,fa3,g0);       \
        MM(0,1,fa0,g1); MM(1,1,fa1,g1); MM(2,1,fa2,g1); MM(3,1,fa3,g1);       \
        __builtin_amdgcn_s_setprio(0);                                        \
        BAR;                                                                  \
        /* ph2 */                                                             \
        g0 = *(const short8*)(bp + Bbase + 2048);                             \
        g1 = *(const short8*)(bp + Bbase + 3072);                             \
        S2; S3;                                                               \
        BAR;                                                                  \
        __builtin_amdgcn_s_setprio(1);                                        \
        MM(0,2,fa0,g0); MM(1,2,fa1,g0); MM(2,2,fa2,g0); MM(3,2,fa3,g0);       \
        MM(0,3,fa0,g1); MM(1,3,fa1,g1); MM(2,3,fa2,g1); MM(3,3,fa3,g1);       \
        __builtin_amdgcn_s_setprio(0);                                        \
        BAR;                                                                  \
        /* ph3 */                                                             \
        g0 = *(const short8*)(bp + Bbase + 4096);                             \
        g1 = *(const short8*)(bp + Bbase + 5120);                             \
        S4;                                                                   \
        BAR;                                                                  \
        __builtin_amdgcn_s_setprio(1);                                        \
        MM(0,4,fa0,g0); MM(1,4,fa1,g0); MM(2,4,fa2,g0); MM(3,4,fa3,g0);       \
        MM(0,5,fa0,g1); MM(1,5,fa1,g1); MM(2,5,fa2,g1); MM(3,5,fa3,g1);       \
        __builtin_amdgcn_s_setprio(0);                                        \
        BAR;                                                                  \
        /* ph4 */                                                             \
        g0 = *(const short8*)(bp + Bbase + 6144);                             \
        g1 = *(const short8*)(bp + Bbase + 7168);                             \
        S5;                                                                   \
        BAR;                                                                  \
        __builtin_amdgcn_s_setprio(1);                                        \
        MM(0,6,fa0,g0); MM(1,6,fa1,g0); MM(2,6,fa2,g0); MM(3,6,fa3,g0);       \
        MM(0,7,fa0,g1); MM(1,7,fa1,g1); MM(2,7,fa2,g1); MM(3,7,fa3,g1);       \
        __builtin_amdgcn_s_setprio(0);                                        \
        BAR;                                                                  \
    } while (0)

#define STG(n) gload16(sp##n + ko2, smem + nbuf + (size_t)tid * 16 + (n) * 8192)

    // prologue: stage steps 0 and 1 fully
    {
        char* lb0 = smem + (size_t)tid * 16;
        gload16(sp0, lb0);           gload16(sp1, lb0 + 8192);
        gload16(sp2, lb0 + 16384);   gload16(sp3, lb0 + 24576);
        gload16(sp4, lb0 + 32768);   gload16(sp5, lb0 + 40960);
        char* lb1 = smem + 49152 + (size_t)tid * 16;
        gload16(sp0 + BK, lb1);          gload16(sp1 + BK, lb1 + 8192);
        gload16(sp2 + BK, lb1 + 16384);  gload16(sp3 + BK, lb1 + 24576);
        gload16(sp4 + BK, lb1 + 32768);  gload16(sp5 + BK, lb1 + 40960);
    }

    for (int t = 0; t < 22; ++t) {
        int cbuf = (t % 3) * 49152;
        int nbuf = ((t + 2) % 3) * 49152;
        size_t ko2 = (size_t)(t + 2) * BK;
        STEP(cbuf, STG(0), STG(1), STG(2), STG(3), STG(4), STG(5), "6");
    }
    STEP(49152, , , , , , , "6");     // t = 22 (buf 1), no staging
    STEP(98304, , , , , , , "0");     // t = 23 (buf 2)
#undef STG
#undef STEP
#undef MM

    __syncthreads();
    // epilogue: H-wave wp combines with T-wave wp via swizzled LDS exchange.
    float* bwv = (float*)(smem + 32768);          // [256]
    int*   bwt = (int*)(smem + 33792);            // [256]
    int wp = w & 3;
    char* xrow = smem + (wp * 64 + l) * 128;      // 32KB exchange region
    int qsw = l & 7;

#define XW(q, v) *(f32x4*)(xrow + (((q) ^ qsw) * 16)) = (v)
#define XR(q)    *(const f32x4*)(xrow + (((q) ^ qsw) * 16))

#define ASTEP(ii, jj, rr, TQ)                                                 \
        { float h = a##ii##jj[rr]; float tv = (TQ)[rr];                       \
          bool ok = (h > THRESH) && (tv > THRESH);                            \
          float sc = ok ? 0.5f * (h + tv) : -INFINITY;                        \
          if (sc > bv) { bv = sc; bt = jj * 16 + l15; } }

#define AMX(ii, rr)                                                           \
    {   float bv = -INFINITY; int bt = 0x7fffffff;                            \
        ASTEP(ii, 0, rr, t0) ASTEP(ii, 1, rr, t1)                             \
        ASTEP(ii, 2, rr, t2) ASTEP(ii, 3, rr, t3)                             \
        ASTEP(ii, 4, rr, t4) ASTEP(ii, 5, rr, t5)                             \
        ASTEP(ii, 6, rr, t6) ASTEP(ii, 7, rr, t7)                             \
        for (int m = 1; m < 16; m <<= 1) {                                    \
            float v2 = __shfl_xor(bv, m); int q2 = __shfl_xor(bt, m);         \
            if (v2 > bv || (v2 == bv && q2 < bt)) { bv = v2; bt = q2; }       \
        }                                                                     \
        if (l15 == 0) { int p = qr * 64 + ii * 16 + lg * 4 + rr;              \
            bwv[p] = bv; bwt[p] = bt; }                                       \
    }

#define EPI(ii)                                                               \
    if (w >= 4) { XW(0, a##ii##0); XW(1, a##ii##1); XW(2, a##ii##2);          \
                  XW(3, a##ii##3); XW(4, a##ii##4); XW(5, a##ii##5);          \
                  XW(6, a##ii##6); XW(7, a##ii##7); }                         \
    __syncthreads();                                                          \
    if (w < 4) {                                                              \
        f32x4 t0 = XR(0), t1 = XR(1), t2 = XR(2), t3 = XR(3);                 \
        f32x4 t4 = XR(4), t5 = XR(5), t6 = XR(6), t7 = XR(7);                 \
        AMX(ii, 0) AMX(ii, 1) AMX(ii, 2) AMX(ii, 3)                           \
    }                                                                         \
    __syncthreads();

    EPI(0)
    EPI(1)
    EPI(2)
    EPI(3)
#undef EPI
#undef AMX
#undef ASTEP
#undef XW
#undef XR

    if (tid < 256) {
        float v = bwv[tid]; int t1 = bwt[tid];
        int grow = b * PP + pblk * 256 + tid;
        cand_v[(size_t)grow * 4 + tblk] = v;
        cand_t[(size_t)grow * 4 + tblk] = (v > -INFINITY) ? (tblk * 128 + t1) : 0x7fffffff;
    }
}

// ---------------- stage 3: fused merge + per-row NLL -------------------------
// block = 256 = 4 waves, one row per wave. Lanes 0-3 merge the 4 t-block
// candidates; then wave-wide log-softmax over C=97.
__global__ void nll_kernel(const float* __restrict__ preds,
                           const float* __restrict__ cand_v,
                           const int* __restrict__ cand_t,
                           const int* __restrict__ rel,
                           float* __restrict__ partials) {
    int w = threadIdx.x >> 6, l = threadIdx.x & 63;
    int row = blockIdx.x * 4 + w;
    const float* x = preds + (size_t)row * CC;

    float v = (l < 4) ? cand_v[(size_t)row * 4 + l] : -INFINITY;
    int  tt = (l < 4) ? cand_t[(size_t)row * 4 + l] : 0x7fffffff;
#pragma unroll
    for (int m = 1; m < 4; m <<= 1) {
        float v2 = __shfl_xor(v, m); int t2 = __shfl_xor(tt, m);
        if (v2 > v || (v2 == v && t2 < tt)) { v = v2; tt = t2; }
    }
    int bb = row >> 9;
    int tg = 0;
    if (l == 0 && v > -INFINITY) tg = rel[bb * TT + tt];
    tg = __shfl(tg, 0);

    float a = x[l];
    float b2 = (l + 64 < CC) ? x[l + 64] : -INFINITY;
    float mx = fmaxf(a, b2);
    for (int m = 32; m; m >>= 1) mx = fmaxf(mx, __shfl_xor(mx, m));
    float e = __expf(a - mx) + ((l + 64 < CC) ? __expf(b2 - mx) : 0.0f);
    for (int m = 32; m; m >>= 1) e += __shfl_xor(e, m);

    __shared__ float part[4];
    if (l == 0) part[w] = mx + logf(e) - x[tg];
    __syncthreads();
    if (threadIdx.x == 0)
        partials[blockIdx.x] = part[0] + part[1] + part[2] + part[3];
}

// ---------------- stage 4: final mean ----------------------------------------
__global__ void final_reduce_kernel(const float* __restrict__ partials, int n,
                                    float* __restrict__ out) {
    float s = 0.f;
    for (int i = threadIdx.x; i < n; i += 256) s += partials[i];
    for (int m = 32; m; m >>= 1) s += __shfl_xor(s, m);
    __shared__ float ps[4];
    if ((threadIdx.x & 63) == 0) ps[threadIdx.x >> 6] = s;
    __syncthreads();
    if (threadIdx.x == 0)
        out[0] = (ps[0] + ps[1] + ps[2] + ps[3]) / (float)(BB * PP);
}

extern "C" void kernel_launch(void* const* d_in, const int* in_sizes, int n_in,
                              void* d_out, int out_size, void* d_ws, size_t ws_size,
                              hipStream_t stream) {
    const float* pairs = (const float*)d_in[0];  // [B,P,1536]
    const float* preds = (const float*)d_in[1];  // [B,P,97]
    const float* trip  = (const float*)d_in[2];  // [B,T,1537]
    float* out = (float*)d_out;

    char* ws = (char*)d_ws;
    size_t vec_bytes = (size_t)BB * PP * DD * sizeof(__hip_bfloat16);  // 25,165,824
    __hip_bfloat16* ph = (__hip_bfloat16*)(ws);
    __hip_bfloat16* pt = (__hip_bfloat16*)(ws + vec_bytes);
    __hip_bfloat16* gh = (__hip_bfloat16*)(ws + 2 * vec_bytes);
    __hip_bfloat16* gt = (__hip_bfloat16*)(ws + 3 * vec_bytes);
    char* p = ws + 4 * vec_bytes;
    int* rel = (int*)p;              p += (size_t)BB * TT * sizeof(int);        // 64KB
    float* cand_v = (float*)p;       p += (size_t)BB * PP * 4 * sizeof(float);  // 256KB
    int* cand_t = (int*)p;           p += (size_t)BB * PP * 4 * sizeof(int);    // 256KB
    float* partials = (float*)p;                                                // 16KB

    norm_pairs_kernel<<<BB * PP, 256, 0, stream>>>(pairs, ph, pt);
    norm_trip_kernel<<<BB * TT, 256, 0, stream>>>(trip, gh, gt, rel);
    match_kernel<<<BB * 8, 512, 0, stream>>>(ph, pt, gh, gt, cand_v, cand_t);
    nll_kernel<<<BB * PP / 4, 256, 0, stream>>>(preds, cand_v, cand_t, rel, partials);
    final_reduce_kernel<<<1, 256, 0, stream>>>(partials, BB * PP / 4, out);
}

// Round 10
// 73.413 us; speedup vs baseline: 5.3367x; 1.4389x over previous
//
#include <hip/hip_runtime.h>
#include <hip/hip_bf16.h>
#include <math.h>

#define DD 768
#define BB 32
#define PP 512
#define TT 512
#define CC 97
#define THRESH 0.8f
#define BK 32

typedef __attribute__((ext_vector_type(8))) short short8;
typedef __attribute__((ext_vector_type(4))) float f32x4;
typedef float4 f4u __attribute__((aligned(4)));

__device__ __forceinline__ short bfc(float x) {
    __hip_bfloat16 h = __float2bfloat16(x);
    return *(short*)&h;
}

// ---------------- fused match: raw fp32 -> bf16 staged dual-GEMM -------------
// Cosine trick: stage RAW values (fp32->bf16 in registers during staging),
// MFMA computes raw dots; per-row sum-of-squares accumulated from the SAME
// fp32 staging registers (norms exact-fp32, dots bf16: error ~0.4% vs 0.2
// absolute discrete margins). Epilogue scales by rsqrt(nA)*rsqrt(nB) then
// thresholds. Deletes both norm kernels + the 100MB bf16 ws round-trip.
// Geometry: 256 blocks, 512 thr = 8 waves, tile 256p x 128t, BK=32, 24 steps.
// Waves 0-3 H, 4-7 T; wave owns 64p x 128t (4x8 frags). 2 x 48KB LDS buffers,
// 1-deep reg prefetch (T14: loads issued before COMPUTE, written after),
// ONE barrier per step. Slot swizzle as verified (chunk c at slot c^((ro>>1)&3)).
__global__ __launch_bounds__(512, 2) void match_kernel(
        const float* __restrict__ pairs, const float* __restrict__ trip,
        float* __restrict__ cand_v, int* __restrict__ cand_t) {
    __shared__ __align__(16) char smem[98304];    // 2 x 48KB (Ah16|At16|Bh8|Bt8)
    __shared__ float norms[768];                  // [Ah256|At256|Bh128|Bt128]

    // XCD swizzle (256 blocks, %8==0 -> bijective); batch b lives on XCD b/4
    int bid = blockIdx.x;
    int swz = (bid & 7) * 32 + (bid >> 3);
    int b = swz >> 3, sub = swz & 7;
    int pblk = sub >> 2, tblk = sub & 3;          // 2 p-blocks x 4 t-blocks

    int tid = threadIdx.x;
    int w = tid >> 6, l = tid & 63;
    int l15 = l & 15, lg = l >> 4;
    int ln = tid & 3;

    const float* pairs_b = pairs + ((size_t)b * PP + pblk * 256) * (2 * DD);
    const float* trip_b  = trip  + ((size_t)b * TT + tblk * 128) * (2 * DD + 1);

    // 6 staging pieces per thread: piece r covers seg=(tid+512r)>>2 of 768
    // 64B-row-segments [Ah rows 0..255 | At 0..255 | Bh 0..127 | Bt 0..127],
    // 16B lane ln; source chunk = ln ^ ((local_row>>1)&3) (swizzle, src side).
    int s0r = tid >> 2;                   int x0 = ln ^ ((s0r >> 1) & 3);
    int s1r = ((tid + 512) >> 2);         int x1 = ln ^ ((s1r >> 1) & 3);
    int s2r = ((tid + 1024) >> 2) - 256;  int x2 = ln ^ ((s2r >> 1) & 3);
    int s3r = ((tid + 1536) >> 2) - 256;  int x3 = ln ^ ((s3r >> 1) & 3);
    int s4r = ((tid + 2048) >> 2) - 512;  int x4 = ln ^ ((s4r >> 1) & 3);
    int s5r = ((tid + 2560) >> 2) - 640;  int x5 = ln ^ ((s5r >> 1) & 3);
    const float* sp0 = pairs_b + (size_t)s0r * 1536 + x0 * 8;
    const float* sp1 = pairs_b + (size_t)s1r * 1536 + x1 * 8;
    const float* sp2 = pairs_b + (size_t)s2r * 1536 + 768 + x2 * 8;
    const float* sp3 = pairs_b + (size_t)s3r * 1536 + 768 + x3 * 8;
    const float* sp4 = trip_b + (size_t)s4r * 1537 + x4 * 8;
    const float* sp5 = trip_b + (size_t)s5r * 1537 + 769 + x5 * 8;
    int dst0 = tid * 16;
    int dst1 = 8192 + tid * 16;
    int dst2 = 16384 + tid * 16;
    int dst3 = 24576 + tid * 16;
    int dst4 = 32768 + tid * 16;
    int dst5 = 40960 + tid * 16;

    float4 va0, va1, va2, va3, va4, va5, vb0, vb1, vb2, vb3, vb4, vb5;
    float sq0 = 0.f, sq1 = 0.f, sq2 = 0.f, sq3 = 0.f, sq4 = 0.f, sq5 = 0.f;

#define LD(r, ko)                                                             \
    do { va##r = *(const f4u*)(sp##r + (ko));                                 \
         vb##r = *(const f4u*)(sp##r + (ko) + 4); } while (0)
#define WRP(r, nb)                                                            \
    do {                                                                      \
        sq##r += va##r.x*va##r.x + va##r.y*va##r.y + va##r.z*va##r.z          \
               + va##r.w*va##r.w + vb##r.x*vb##r.x + vb##r.y*vb##r.y          \
               + vb##r.z*vb##r.z + vb##r.w*vb##r.w;                           \
        short8 pk;                                                            \
        pk[0]=bfc(va##r.x); pk[1]=bfc(va##r.y); pk[2]=bfc(va##r.z);           \
        pk[3]=bfc(va##r.w); pk[4]=bfc(vb##r.x); pk[5]=bfc(vb##r.y);           \
        pk[6]=bfc(vb##r.z); pk[7]=bfc(vb##r.w);                               \
        *(short8*)(smem + (nb) + dst##r) = pk;                                \
    } while (0)

    // read addressing: row pitch 64B; phys slot = lg ^ ((l15>>1)&3)
    int qr = w & 3;
    int Aoff = (w < 4) ? 0 : 16384;
    int Boff = (w < 4) ? 32768 : 40960;
    int slot = (lg ^ ((l15 >> 1) & 3)) * 16;
    int Abase = Aoff + (qr * 64 + l15) * 64 + slot;   // +i*1024
    int Bbase = Boff + l15 * 64 + slot;               // +j*1024

    f32x4 z = {0.f, 0.f, 0.f, 0.f};
    f32x4 a00=z,a01=z,a02=z,a03=z,a04=z,a05=z,a06=z,a07=z;
    f32x4 a10=z,a11=z,a12=z,a13=z,a14=z,a15=z,a16=z,a17=z;
    f32x4 a20=z,a21=z,a22=z,a23=z,a24=z,a25=z,a26=z,a27=z;
    f32x4 a30=z,a31=z,a32=z,a33=z,a34=z,a35=z,a36=z,a37=z;

#define MM(i, j, fa, fb) a##i##j = __builtin_amdgcn_mfma_f32_16x16x32_bf16(fa, fb, a##i##j, 0, 0, 0)
#define COMPUTE(cb)                                                           \
    do {                                                                      \
        const char* bp = smem + (cb);                                         \
        short8 fa0 = *(const short8*)(bp + Abase + 0);                        \
        short8 fa1 = *(const short8*)(bp + Abase + 1024);                     \
        short8 fa2 = *(const short8*)(bp + Abase + 2048);                     \
        short8 fa3 = *(const short8*)(bp + Abase + 3072);                     \
        short8 g0 = *(const short8*)(bp + Bbase + 0);                         \
        short8 g1 = *(const short8*)(bp + Bbase + 1024);                      \
        short8 g2 = *(const short8*)(bp + Bbase + 2048);                      \
        short8 g3 = *(const short8*)(bp + Bbase + 3072);                      \
        __builtin_amdgcn_s_setprio(1);                                        \
        MM(0,0,fa0,g0); MM(1,0,fa1,g0); MM(2,0,fa2,g0); MM(3,0,fa3,g0);       \
        MM(0,1,fa0,g1); MM(1,1,fa1,g1); MM(2,1,fa2,g1); MM(3,1,fa3,g1);       \
        MM(0,2,fa0,g2); MM(1,2,fa1,g2); MM(2,2,fa2,g2); MM(3,2,fa3,g2);       \
        MM(0,3,fa0,g3); MM(1,3,fa1,g3); MM(2,3,fa2,g3); MM(3,3,fa3,g3);       \
        __builtin_amdgcn_s_setprio(0);                                        \
        g0 = *(const short8*)(bp + Bbase + 4096);                             \
        g1 = *(const short8*)(bp + Bbase + 5120);                             \
        g2 = *(const short8*)(bp + Bbase + 6144);                             \
        g3 = *(const short8*)(bp + Bbase + 7168);                             \
        __builtin_amdgcn_s_setprio(1);                                        \
        MM(0,4,fa0,g0); MM(1,4,fa1,g0); MM(2,4,fa2,g0); MM(3,4,fa3,g0);       \
        MM(0,5,fa0,g1); MM(1,5,fa1,g1); MM(2,5,fa2,g1); MM(3,5,fa3,g1);       \
        MM(0,6,fa0,g2); MM(1,6,fa1,g2); MM(2,6,fa2,g2); MM(3,6,fa3,g2);       \
        MM(0,7,fa0,g3); MM(1,7,fa1,g3); MM(2,7,fa2,g3); MM(3,7,fa3,g3);       \
        __builtin_amdgcn_s_setprio(0);                                        \
    } while (0)

    // prologue: tile 0 -> buf0
    LD(0, 0); LD(1, 0); LD(2, 0); LD(3, 0); LD(4, 0); LD(5, 0);
    WRP(0, 0); WRP(1, 0); WRP(2, 0); WRP(3, 0); WRP(4, 0); WRP(5, 0);
    __syncthreads();

#pragma unroll 2
    for (int t = 0; t < 24; ++t) {
        int cb = (t & 1) * 49152;
        int nb = cb ^ 49152;
        if (t < 23) {                     // issue next tile's loads (T14 early)
            size_t ko = (size_t)(t + 1) * BK;
            LD(0, ko); LD(1, ko); LD(2, ko); LD(3, ko); LD(4, ko); LD(5, ko);
        }
        COMPUTE(cb);                      // MFMA on current tile hides HBM
        if (t < 23) {                     // write-late: sq accum + cvt + ds_write
            WRP(0, nb); WRP(1, nb); WRP(2, nb);
            WRP(3, nb); WRP(4, nb); WRP(5, nb);
        }
        __syncthreads();
    }
#undef COMPUTE
#undef MM
#undef WRP
#undef LD

    // finalize norms: quad-reduce (lanes ln=0..3 share a row-segment)
    sq0 += __shfl_xor(sq0, 1); sq0 += __shfl_xor(sq0, 2);
    sq1 += __shfl_xor(sq1, 1); sq1 += __shfl_xor(sq1, 2);
    sq2 += __shfl_xor(sq2, 1); sq2 += __shfl_xor(sq2, 2);
    sq3 += __shfl_xor(sq3, 1); sq3 += __shfl_xor(sq3, 2);
    sq4 += __shfl_xor(sq4, 1); sq4 += __shfl_xor(sq4, 2);
    sq5 += __shfl_xor(sq5, 1); sq5 += __shfl_xor(sq5, 2);
    if (ln == 0) {
        norms[tid >> 2] = sq0;
        norms[(tid + 512) >> 2] = sq1;
        norms[(tid + 1024) >> 2] = sq2;
        norms[(tid + 1536) >> 2] = sq3;
        norms[(tid + 2048) >> 2] = sq4;
        norms[(tid + 2560) >> 2] = sq5;
    }
    __syncthreads();

    // scale raw dots -> cosines: a[i][j][r] *= rsqrt(nA[p]) * rsqrt(nB[t])
    {
        const float* nA = norms + ((w < 4) ? 0 : 256);
        const float* nB = norms + ((w < 4) ? 512 : 640);
        float ivB0 = rsqrtf(nB[0 * 16 + l15]), ivB1 = rsqrtf(nB[1 * 16 + l15]);
        float ivB2 = rsqrtf(nB[2 * 16 + l15]), ivB3 = rsqrtf(nB[3 * 16 + l15]);
        float ivB4 = rsqrtf(nB[4 * 16 + l15]), ivB5 = rsqrtf(nB[5 * 16 + l15]);
        float ivB6 = rsqrtf(nB[6 * 16 + l15]), ivB7 = rsqrtf(nB[7 * 16 + l15]);
#define SCJ(ii, jj) { a##ii##jj[0] *= s0 * ivB##jj; a##ii##jj[1] *= s1 * ivB##jj; \
                      a##ii##jj[2] *= s2 * ivB##jj; a##ii##jj[3] *= s3 * ivB##jj; }
#define SCA(ii) { float s0 = rsqrtf(nA[qr * 64 + ii * 16 + lg * 4 + 0]);      \
                  float s1 = rsqrtf(nA[qr * 64 + ii * 16 + lg * 4 + 1]);      \
                  float s2 = rsqrtf(nA[qr * 64 + ii * 16 + lg * 4 + 2]);      \
                  float s3 = rsqrtf(nA[qr * 64 + ii * 16 + lg * 4 + 3]);      \
                  SCJ(ii,0) SCJ(ii,1) SCJ(ii,2) SCJ(ii,3)                     \
                  SCJ(ii,4) SCJ(ii,5) SCJ(ii,6) SCJ(ii,7) }
        SCA(0) SCA(1) SCA(2) SCA(3)
#undef SCA
#undef SCJ
    }
    __syncthreads();

    // epilogue: H-wave wp combines with T-wave wp via swizzled LDS exchange.
    float* bwv = (float*)(smem + 32768);          // [256]
    int*   bwt = (int*)(smem + 33792);            // [256]
    int wp = w & 3;
    char* xrow = smem + (wp * 64 + l) * 128;      // 32KB exchange region
    int qsw = l & 7;

#define XW(q, v) *(f32x4*)(xrow + (((q) ^ qsw) * 16)) = (v)
#define XR(q)    *(const f32x4*)(xrow + (((q) ^ qsw) * 16))

#define ASTEP(ii, jj, rr, TQ)                                                 \
        { float h = a##ii##jj[rr]; float tv = (TQ)[rr];                       \
          bool ok = (h > THRESH) && (tv > THRESH);                            \
          float sc = ok ? 0.5f * (h + tv) : -INFINITY;                        \
          if (sc > bv) { bv = sc; bt = jj * 16 + l15; } }

#define AMX(ii, rr)                                                           \
    {   float bv = -INFINITY; int bt = 0x7fffffff;                            \
        ASTEP(ii, 0, rr, t0) ASTEP(ii, 1, rr, t1)                             \
        ASTEP(ii, 2, rr, t2) ASTEP(ii, 3, rr, t3)                             \
        ASTEP(ii, 4, rr, t4) ASTEP(ii, 5, rr, t5)                             \
        ASTEP(ii, 6, rr, t6) ASTEP(ii, 7, rr, t7)                             \
        for (int m = 1; m < 16; m <<= 1) {                                    \
            float v2 = __shfl_xor(bv, m); int q2 = __shfl_xor(bt, m);         \
            if (v2 > bv || (v2 == bv && q2 < bt)) { bv = v2; bt = q2; }       \
        }                                                                     \
        if (l15 == 0) { int p = qr * 64 + ii * 16 + lg * 4 + rr;              \
            bwv[p] = bv; bwt[p] = bt; }                                       \
    }

#define EPI(ii)                                                               \
    if (w >= 4) { XW(0, a##ii##0); XW(1, a##ii##1); XW(2, a##ii##2);          \
                  XW(3, a##ii##3); XW(4, a##ii##4); XW(5, a##ii##5);          \
                  XW(6, a##ii##6); XW(7, a##ii##7); }                         \
    __syncthreads();                                                          \
    if (w < 4) {                                                              \
        f32x4 t0 = XR(0), t1 = XR(1), t2 = XR(2), t3 = XR(3);                 \
        f32x4 t4 = XR(4), t5 = XR(5), t6 = XR(6), t7 = XR(7);                 \
        AMX(ii, 0) AMX(ii, 1) AMX(ii, 2) AMX(ii, 3)                           \
    }                                                                         \
    __syncthreads();

    EPI(0)
    EPI(1)
    EPI(2)
    EPI(3)
#undef EPI
#undef AMX
#undef ASTEP
#undef XW
#undef XR

    if (tid < 256) {
        float v = bwv[tid]; int t1 = bwt[tid];
        int grow = b * PP + pblk * 256 + tid;
        cand_v[(size_t)grow * 4 + tblk] = v;
        cand_t[(size_t)grow * 4 + tblk] = (v > -INFINITY) ? (tblk * 128 + t1) : 0x7fffffff;
    }
}

// ---------------- stage 3: fused merge + per-row NLL -------------------------
// block = 256 = 4 waves, one row per wave. Lanes 0-3 merge the 4 t-block
// candidates; rel id read directly from trip column D; wave log-softmax C=97.
__global__ void nll_kernel(const float* __restrict__ preds,
                           const float* __restrict__ cand_v,
                           const int* __restrict__ cand_t,
                           const float* __restrict__ trip,
                           float* __restrict__ partials) {
    int w = threadIdx.x >> 6, l = threadIdx.x & 63;
    int row = blockIdx.x * 4 + w;
    const float* x = preds + (size_t)row * CC;

    float v = (l < 4) ? cand_v[(size_t)row * 4 + l] : -INFINITY;
    int  tt = (l < 4) ? cand_t[(size_t)row * 4 + l] : 0x7fffffff;
#pragma unroll
    for (int m = 1; m < 4; m <<= 1) {
        float v2 = __shfl_xor(v, m); int t2 = __shfl_xor(tt, m);
        if (v2 > v || (v2 == v && t2 < tt)) { v = v2; tt = t2; }
    }
    int bb = row >> 9;
    int tg = 0;
    if (l == 0 && v > -INFINITY)
        tg = (int)trip[((size_t)bb * TT + tt) * (2 * DD + 1) + DD];
    tg = __shfl(tg, 0);

    float a = x[l];
    float b2 = (l + 64 < CC) ? x[l + 64] : -INFINITY;
    float mx = fmaxf(a, b2);
    for (int m = 32; m; m >>= 1) mx = fmaxf(mx, __shfl_xor(mx, m));
    float e = __expf(a - mx) + ((l + 64 < CC) ? __expf(b2 - mx) : 0.0f);
    for (int m = 32; m; m >>= 1) e += __shfl_xor(e, m);

    __shared__ float part[4];
    if (l == 0) part[w] = mx + logf(e) - x[tg];
    __syncthreads();
    if (threadIdx.x == 0)
        partials[blockIdx.x] = part[0] + part[1] + part[2] + part[3];
}

// ---------------- stage 4: final mean ----------------------------------------
__global__ void final_reduce_kernel(const float* __restrict__ partials, int n,
                                    float* __restrict__ out) {
    float s = 0.f;
    for (int i = threadIdx.x; i < n; i += 256) s += partials[i];
    for (int m = 32; m; m >>= 1) s += __shfl_xor(s, m);
    __shared__ float ps[4];
    if ((threadIdx.x & 63) == 0) ps[threadIdx.x >> 6] = s;
    __syncthreads();
    if (threadIdx.x == 0)
        out[0] = (ps[0] + ps[1] + ps[2] + ps[3]) / (float)(BB * PP);
}

extern "C" void kernel_launch(void* const* d_in, const int* in_sizes, int n_in,
                              void* d_out, int out_size, void* d_ws, size_t ws_size,
                              hipStream_t stream) {
    const float* pairs = (const float*)d_in[0];  // [B,P,1536]
    const float* preds = (const float*)d_in[1];  // [B,P,97]
    const float* trip  = (const float*)d_in[2];  // [B,T,1537]
    float* out = (float*)d_out;

    char* p = (char*)d_ws;
    float* cand_v = (float*)p;       p += (size_t)BB * PP * 4 * sizeof(float);  // 256KB
    int* cand_t = (int*)p;           p += (size_t)BB * PP * 4 * sizeof(int);    // 256KB
    float* partials = (float*)p;                                                // 16KB

    match_kernel<<<BB * 8, 512, 0, stream>>>(pairs, trip, cand_v, cand_t);
    nll_kernel<<<BB * PP / 4, 256, 0, stream>>>(preds, cand_v, cand_t, trip, partials);
    final_reduce_kernel<<<1, 256, 0, stream>>>(partials, BB * PP / 4, out);
}